// Round 3
// baseline (980.808 us; speedup 1.0000x reference)
//
#include <hip/hip_runtime.h>

static constexpr int N  = 128;   // N_STATE
static constexpr int S  = 8192;  // SEQ
static constexpr int L  = 128;   // chunk length
static constexpr int NC = 64;    // S/L
static constexpr int OD = 1000;  // OUT_DIM
static constexpr int KSPLIT = 8;
#define SCL 0.25f                // 1/sqrt(D_HEAD=16)

typedef unsigned short u16;
typedef __attribute__((ext_vector_type(4))) unsigned short us4;
typedef __attribute__((ext_vector_type(8))) unsigned short us8;
typedef __attribute__((ext_vector_type(8))) short bf16x8;   // 8 bf16 = 4 VGPRs
typedef __attribute__((ext_vector_type(4))) float f32x4;

__device__ __forceinline__ u16 f2bf(float x){
  unsigned u = __float_as_uint(x);
  u += 0x7FFFu + ((u >> 16) & 1u);   // RNE to bf16
  return (u16)(u >> 16);
}
__device__ __forceinline__ float bf2f(u16 h){
  return __uint_as_float(((unsigned)h) << 16);
}

// ---- QT[1] = GA^T ----
__global__ void k_copyT(const float* __restrict__ GA, float* __restrict__ QT1){
  int idx = blockIdx.x*256 + threadIdx.x;
  int m = idx >> 7, n = idx & 127;
  QT1[idx] = GA[n*N + m];
}

// ---- QT[mlev+i] = QT[mlev] @ QT[i] ----
__global__ __launch_bounds__(256) void k_powmm(float* QT, int mlev){
  int i = blockIdx.z + 1;
  const float* Am = QT + (size_t)mlev*(N*N);
  const float* Ai = QT + (size_t)i*(N*N);
  float* C = QT + (size_t)(mlev+i)*(N*N);
  __shared__ __align__(16) float As[16][68];
  __shared__ __align__(16) float Bs[16][68];
  int bm = blockIdx.y, bn = blockIdx.x;
  int tx = threadIdx.x, ty = threadIdx.y;
  int tid = ty*16 + tx;
  float acc[4][4] = {};
  for (int kt = 0; kt < N; kt += 16){
    int row = tid >> 2, kc = (tid & 3) << 2;
    float4 av = *(const float4*)(Am + (size_t)(bm*64+row)*N + kt + kc);
    As[kc+0][row]=av.x; As[kc+1][row]=av.y; As[kc+2][row]=av.z; As[kc+3][row]=av.w;
    int bk = tid >> 4, c0 = (tid & 15) << 2;
    *(float4*)&Bs[bk][c0] = *(const float4*)(Ai + (size_t)(kt+bk)*N + bn*64 + c0);
    __syncthreads();
#pragma unroll
    for (int kk = 0; kk < 16; ++kk){
      float4 a = *(const float4*)&As[kk][ty*4];
      float4 b = *(const float4*)&Bs[kk][tx*4];
      float aa[4]={a.x,a.y,a.z,a.w}, bb[4]={b.x,b.y,b.z,b.w};
#pragma unroll
      for (int ii=0; ii<4; ++ii)
#pragma unroll
        for (int jj=0; jj<4; ++jj) acc[ii][jj] += aa[ii]*bb[jj];
    }
    __syncthreads();
  }
#pragma unroll
  for (int ii=0; ii<4; ++ii){
    float4 vst = make_float4(acc[ii][0],acc[ii][1],acc[ii][2],acc[ii][3]);
    *(float4*)(C + (size_t)(bm*64+ty*4+ii)*N + bn*64 + tx*4) = vst;
  }
}

// ---- g[k] = GA^k GB ----
__global__ void k_g(const float* __restrict__ QT, const float* __restrict__ GB,
                    float* __restrict__ g){
  int kb = blockIdx.x;
  int n = threadIdx.x;
  if (kb == 0){ g[n] = GB[n]; return; }
  const float* Qk = QT + (size_t)kb*(N*N);
  float acc = 0.0f;
  for (int m = 0; m < N; ++m) acc += Qk[m*N + n]*GB[m];
  g[kb*N + n] = acc;
}

// ---- within-chunk causal conv ----
__global__ __launch_bounds__(256) void k_fill_local(const float* __restrict__ fq,
                             const float* __restrict__ fk, const float* __restrict__ fv,
                             const float* __restrict__ g, float* __restrict__ cs){
  int tile = blockIdx.x;
  int s = blockIdx.y, j = blockIdx.z;
  const float* f = (s==0)? fq : (s==1)? fk : fv;
  __shared__ float flp[256];
  __shared__ __align__(16) float Bs[16][68];
  int tx = threadIdx.x, ty = threadIdx.y;
  int tid = ty*16 + tx;
  flp[tid] = (tid < 128) ? 0.0f : f[j*L + tid - 128];
  int ti = tile >> 1, tj = tile & 1;
  float acc[4][4] = {};
  int kmax = (ti == 0) ? 64 : 128;
  for (int kt = 0; kt < kmax; kt += 16){
    int bk = tid >> 4, c0 = (tid & 15) << 2;
    *(float4*)&Bs[bk][c0] = *(const float4*)(g + (size_t)(kt+bk)*N + tj*64 + c0);
    __syncthreads();
#pragma unroll
    for (int kk = 0; kk < 16; ++kk){
      float4 b = *(const float4*)&Bs[kk][tx*4];
      int base = 128 + ti*64 + ty*4 - kt - kk;
      float aa[4] = {flp[base], flp[base+1], flp[base+2], flp[base+3]};
      float bb[4] = {b.x, b.y, b.z, b.w};
#pragma unroll
      for (int ii=0; ii<4; ++ii)
#pragma unroll
        for (int jj=0; jj<4; ++jj) acc[ii][jj] += aa[ii]*bb[jj];
    }
    __syncthreads();
  }
#pragma unroll
  for (int ii=0; ii<4; ++ii){
    int row = ti*64 + ty*4 + ii;
    float4 vst = make_float4(acc[ii][0],acc[ii][1],acc[ii][2],acc[ii][3]);
    *(float4*)(cs + ((size_t)s*S + (size_t)j*L + row)*N + tj*64 + tx*4) = vst;
  }
}

// ---- sequential chunk-boundary scan ----
__global__ void k_bscan(const float* __restrict__ QT, const float* __restrict__ cs,
                        float* __restrict__ bounds){
  __shared__ float bc[3][N];
  __shared__ float bnx[3][N];
  int tid = threadIdx.x;
  int s = tid >> 7, n = tid & 127;
  const float* QL = QT + (size_t)L*(N*N);
  bc[s][n] = 0.0f;
  bounds[(0*3+s)*N + n] = 0.0f;
  __syncthreads();
  for (int j = 0; j < NC; ++j){
    float acc = cs[((size_t)s*S + (size_t)j*L + 127)*N + n];
    for (int m = 0; m < N; ++m) acc += QL[m*N+n]*bc[s][m];
    bnx[s][n] = acc;
    bounds[((j+1)*3+s)*N + n] = acc;
    __syncthreads();
    bc[s][n] = bnx[s][n];
    __syncthreads();
  }
}

// ---- boundary fill: cs[s][jL+i] += GA^{i+1} b_j  (4-task register blocking) ----
__global__ __launch_bounds__(256) void k_fill_bound(const float* __restrict__ QT,
                          const float* __restrict__ bounds, float* __restrict__ cs){
  int i = blockIdx.x;
  int jg = blockIdx.y;
  __shared__ float Qs[N*N];
  int tid = threadIdx.x;
  int p = tid >> 7, n = tid & 127;
  const float* Qg = QT + (size_t)(i+1)*(N*N);
  for (int idx = tid; idx < N*N; idx += 256) Qs[idx] = Qg[idx];
  __syncthreads();
  for (int r4 = 0; r4 < 24; r4 += 4){
    int task0 = jg*48 + p*24 + r4;
    const float* b0 = bounds + (size_t)task0*N;
    const float* b1 = b0 + N;
    const float* b2 = b0 + 2*N;
    const float* b3 = b0 + 3*N;
    float a0=0.f, a1=0.f, a2=0.f, a3=0.f;
#pragma unroll 4
    for (int m = 0; m < N; ++m){
      float q = Qs[m*N + n];
      a0 += q*b0[m]; a1 += q*b1[m]; a2 += q*b2[m]; a3 += q*b3[m];
    }
    float av[4] = {a0, a1, a2, a3};
#pragma unroll
    for (int q4 = 0; q4 < 4; ++q4){
      int task = task0 + q4;
      int j = task/3, s2 = task - 3*j;
      cs[((size_t)s2*S + (size_t)j*L + i)*N + n] += av[q4];
    }
  }
}

// ---- split q,k states into bf16 hi/lo (natural [2*S][N] layout) ----
__global__ void k_split_qk(const float* __restrict__ cs,
                           u16* __restrict__ sh, u16* __restrict__ sl){
  size_t i = ((size_t)blockIdx.x*256 + threadIdx.x) << 2;
  float4 v = *(const float4*)(cs + i);
  us4 h, l;
  h[0]=f2bf(v.x); l[0]=f2bf(v.x - bf2f(h[0]));
  h[1]=f2bf(v.y); l[1]=f2bf(v.y - bf2f(h[1]));
  h[2]=f2bf(v.z); l[2]=f2bf(v.z - bf2f(h[2]));
  h[3]=f2bf(v.w); l[3]=f2bf(v.w - bf2f(h[3]));
  *(us4*)(sh + i) = h;
  *(us4*)(sl + i) = l;
}

// ---- split v states into bf16 hi/lo, TRANSPOSED to [N][S] ----
__global__ __launch_bounds__(256) void k_split_vT(const float* __restrict__ vs,
                           u16* __restrict__ vth, u16* __restrict__ vtl){
  __shared__ u16 Th[128*72];
  __shared__ u16 Tl[128*72];
  int t0 = blockIdx.x * 64;
  int tid = threadIdx.x;
  for (int c = tid; c < 2048; c += 256){
    int i = c >> 5, n0 = (c & 31) << 2;
    float4 v = *(const float4*)(vs + (size_t)(t0 + i)*N + n0);
    u16 h;
    h = f2bf(v.x); Th[(n0+0)*72 + i] = h; Tl[(n0+0)*72 + i] = f2bf(v.x - bf2f(h));
    h = f2bf(v.y); Th[(n0+1)*72 + i] = h; Tl[(n0+1)*72 + i] = f2bf(v.y - bf2f(h));
    h = f2bf(v.z); Th[(n0+2)*72 + i] = h; Tl[(n0+2)*72 + i] = f2bf(v.z - bf2f(h));
    h = f2bf(v.w); Th[(n0+3)*72 + i] = h; Tl[(n0+3)*72 + i] = f2bf(v.w - bf2f(h));
  }
  __syncthreads();
  for (int c = tid; c < 1024; c += 256){
    int n = c >> 3, tc = (c & 7) << 3;
    *(us8*)(vth + (size_t)n*S + t0 + tc) = *(const us8*)&Th[n*72 + tc];
    *(us8*)(vtl + (size_t)n*S + t0 + tc) = *(const us8*)&Tl[n*72 + tc];
  }
}

// ---- scores via split-bf16 MFMA, zero-LDS main loop ----
// A/B fragments loaded directly from global (qk hi/lo is L2/L3-resident).
// Epilogue: one LDS bounce -> coalesced attn stores + per-(row, col-block) stats.
__global__ __launch_bounds__(256) void k_score_mfma(
    const u16* __restrict__ qh, const u16* __restrict__ ql,
    const u16* __restrict__ kh, const u16* __restrict__ kl,
    float* __restrict__ attn, float* __restrict__ pmax, float* __restrict__ psum){
  __shared__ __align__(16) float bounce[128*132];   // 67584 B
  int bm = blockIdx.y, bn = blockIdx.x;
  int tid = threadIdx.x;
  int lane = tid & 63, w = tid >> 6;
  int wr = w >> 1, wc = w & 1;
  f32x4 acc[4][4] = {};
  int rA = bm*128 + wr*64 + (lane & 15);
  int rB = bn*128 + wc*64 + (lane & 15);
  int kg = (lane >> 4) << 3;
  for (int kt = 0; kt < N; kt += 32){
    int k = kt + kg;
    bf16x8 ah[4], al[4], bh[4], bl[4];
#pragma unroll
    for (int i = 0; i < 4; ++i){
      ah[i] = *(const bf16x8*)(qh + (size_t)(rA + i*16)*N + k);
      al[i] = *(const bf16x8*)(ql + (size_t)(rA + i*16)*N + k);
      bh[i] = *(const bf16x8*)(kh + (size_t)(rB + i*16)*N + k);
      bl[i] = *(const bf16x8*)(kl + (size_t)(rB + i*16)*N + k);
    }
#pragma unroll
    for (int mi = 0; mi < 4; ++mi)
#pragma unroll
      for (int ni = 0; ni < 4; ++ni){
        acc[mi][ni] = __builtin_amdgcn_mfma_f32_16x16x32_bf16(ah[mi], bh[ni], acc[mi][ni], 0,0,0);
        acc[mi][ni] = __builtin_amdgcn_mfma_f32_16x16x32_bf16(ah[mi], bl[ni], acc[mi][ni], 0,0,0);
        acc[mi][ni] = __builtin_amdgcn_mfma_f32_16x16x32_bf16(al[mi], bh[ni], acc[mi][ni], 0,0,0);
      }
  }
  // epilogue: bounce full tile (C map: col=lane&15, row=(lane>>4)*4+reg)
  int r0l = wr*64 + ((lane >> 4) << 2);
  int c0l = wc*64 + (lane & 15);
#pragma unroll
  for (int mi = 0; mi < 4; ++mi)
#pragma unroll
    for (int ni = 0; ni < 4; ++ni)
#pragma unroll
      for (int r = 0; r < 4; ++r)
        bounce[(r0l + mi*16 + r)*132 + c0l + ni*16] = acc[mi][ni][r]*SCL;
  __syncthreads();
  for (int c = tid; c < 4096; c += 256){       // 128 rows * 32 float4, coalesced
    int r = c >> 5, c4 = (c & 31) << 2;
    *(float4*)(attn + (size_t)(bm*128 + r)*S + bn*128 + c4) =
        *(const float4*)&bounce[r*132 + c4];
  }
  if (tid < 128){
    const float* row = &bounce[tid*132];
    float m = -3.0e38f;
    for (int c4 = 0; c4 < 128; c4 += 4){
      float4 v = *(const float4*)&row[c4];
      m = fmaxf(m, fmaxf(fmaxf(v.x,v.y), fmaxf(v.z,v.w)));
    }
    float sm = 0.0f;
    for (int c4 = 0; c4 < 128; c4 += 4){
      float4 v = *(const float4*)&row[c4];
      sm += __expf(v.x-m) + __expf(v.y-m) + __expf(v.z-m) + __expf(v.w-m);
    }
    pmax[(size_t)bn*S + bm*128 + tid] = m;
    psum[(size_t)bn*S + bm*128 + tid] = sm;
  }
}

// ---- merge per-col-block partials -> per-row (max, 1/Z) ----
__global__ void k_rowstat(const float* __restrict__ pmax, const float* __restrict__ psum,
                          float* __restrict__ rowm, float* __restrict__ rowinv){
  int t = blockIdx.x*256 + threadIdx.x;   // row
  float m = -3.0e38f;
  for (int b = 0; b < 64; ++b) m = fmaxf(m, pmax[(size_t)b*S + t]);
  float Z = 0.0f;
  for (int b = 0; b < 64; ++b) Z += psum[(size_t)b*S + t]*__expf(pmax[(size_t)b*S + t] - m);
  rowm[t] = m;
  rowinv[t] = 1.0f/Z;
}

// ---- fused normalize + context via split-bf16 MFMA ----
// BK=64 staging (A hi/lo only in LDS); V fragments direct from global
// (per-kz vT slice is 256 KB, L2-resident across the 64 bm-blocks).
__global__ __launch_bounds__(256) void k_context_mfma(float* __restrict__ attn,
                       const float* __restrict__ rowm, const float* __restrict__ rowinv,
                       const u16* __restrict__ vth, const u16* __restrict__ vtl,
                       float* __restrict__ dst, int mode){
  __shared__ __align__(16) u16 Ah[128*72], Al[128*72];   // 36864 B
  __shared__ float rm[128], ri[128];
  int kz = blockIdx.x, bm = blockIdx.y;
  int tid = threadIdx.x;
  int lane = tid & 63, w = tid >> 6;
  int wr = w >> 1, wc = w & 1;
  const int KC = S / KSPLIT;   // 1024
  int k0 = kz*KC;
  if (tid < 128){ rm[tid] = rowm[bm*128 + tid]; ri[tid] = rowinv[bm*128 + tid]; }
  __syncthreads();
  f32x4 acc[4][4] = {};
  int rA = wr*64 + (lane & 15);
  int nB = wc*64 + (lane & 15);
  int kg = (lane >> 4) << 3;
  for (int ko = 0; ko < KC; ko += 64){
    // stage A: 128x64 raw scores -> exp-normalize -> attn write + hi/lo LDS
    for (int c = tid; c < 2048; c += 256){   // 128 rows * 16 float4
      int r = c >> 4, c4 = (c & 15) << 2;
      size_t gaddr = (size_t)(bm*128 + r)*S + k0 + ko + c4;
      float4 v = *(const float4*)(attn + gaddr);
      float m = rm[r], z = ri[r];
      v.x = __expf(v.x - m)*z; v.y = __expf(v.y - m)*z;
      v.z = __expf(v.z - m)*z; v.w = __expf(v.w - m)*z;
      *(float4*)(attn + gaddr) = v;          // normalized attn output
      us4 h, l;
      h[0]=f2bf(v.x); l[0]=f2bf(v.x - bf2f(h[0]));
      h[1]=f2bf(v.y); l[1]=f2bf(v.y - bf2f(h[1]));
      h[2]=f2bf(v.z); l[2]=f2bf(v.z - bf2f(h[2]));
      h[3]=f2bf(v.w); l[3]=f2bf(v.w - bf2f(h[3]));
      int lo = r*72 + c4;
      *(us4*)&Ah[lo] = h;
      *(us4*)&Al[lo] = l;
    }
    __syncthreads();
#pragma unroll
    for (int k2 = 0; k2 < 2; ++k2){
      int kk = k2*32 + kg;
      bf16x8 ah[4], al[4];
#pragma unroll
      for (int mi = 0; mi < 4; ++mi){
        ah[mi] = *(const bf16x8*)&Ah[(rA + mi*16)*72 + kk];
        al[mi] = *(const bf16x8*)&Al[(rA + mi*16)*72 + kk];
      }
#pragma unroll
      for (int ni = 0; ni < 4; ++ni){
        size_t gb = (size_t)(nB + ni*16)*S + k0 + ko + kk;
        bf16x8 bh = *(const bf16x8*)(vth + gb);
        bf16x8 bl = *(const bf16x8*)(vtl + gb);
#pragma unroll
        for (int mi = 0; mi < 4; ++mi){
          acc[mi][ni] = __builtin_amdgcn_mfma_f32_16x16x32_bf16(ah[mi], bh, acc[mi][ni], 0,0,0);
          acc[mi][ni] = __builtin_amdgcn_mfma_f32_16x16x32_bf16(ah[mi], bl, acc[mi][ni], 0,0,0);
          acc[mi][ni] = __builtin_amdgcn_mfma_f32_16x16x32_bf16(al[mi], bh, acc[mi][ni], 0,0,0);
        }
      }
    }
    __syncthreads();
  }
  int r0 = bm*128 + wr*64 + ((lane >> 4) << 2);
  int c0 = wc*64 + (lane & 15);
  if (mode == 0){
    float* P = dst + (size_t)kz*S*N;
#pragma unroll
    for (int mi = 0; mi < 4; ++mi)
#pragma unroll
      for (int ni = 0; ni < 4; ++ni)
#pragma unroll
        for (int r = 0; r < 4; ++r)
          P[(size_t)(r0 + mi*16 + r)*N + c0 + ni*16] = acc[mi][ni][r];
  } else {
#pragma unroll
    for (int mi = 0; mi < 4; ++mi)
#pragma unroll
      for (int ni = 0; ni < 4; ++ni)
#pragma unroll
        for (int r = 0; r < 4; ++r)
          atomicAdd(&dst[(size_t)(r0 + mi*16 + r)*N + c0 + ni*16], acc[mi][ni][r]);
  }
}

// ---- reduce partials -> ctx ----
__global__ __launch_bounds__(256) void k_reduce(const float* __restrict__ part,
                                                float* __restrict__ ctx){
  size_t idx = (size_t)blockIdx.x*256 + threadIdx.x;
  const float4* p4 = (const float4*)part;
  float4 acc = p4[idx];
  const size_t stride = (size_t)S*N/4;
#pragma unroll
  for (int kz = 1; kz < KSPLIT; ++kz){
    float4 v = p4[(size_t)kz*stride + idx];
    acc.x += v.x; acc.y += v.y; acc.z += v.z; acc.w += v.w;
  }
  ((float4*)ctx)[idx] = acc;
}

// ---- out = ctx @ Wp + bp ----
__global__ __launch_bounds__(256) void k_out(const float* __restrict__ ctx,
                   const float* __restrict__ Wp, const float* __restrict__ bp,
                   float* __restrict__ out){
  __shared__ __align__(16) float As[16][68];
  __shared__ __align__(16) float Bs[16][68];
  int bn = blockIdx.x;
  int bm = blockIdx.y;
  int tx = threadIdx.x, ty = threadIdx.y;
  int tid = ty*16 + tx;
  float acc[4][4] = {};
  for (int kt = 0; kt < N; kt += 16){
    int row = tid >> 2, kc = (tid & 3) << 2;
    float4 av = *(const float4*)(ctx + (size_t)(bm*64+row)*N + kt + kc);
    As[kc+0][row]=av.x; As[kc+1][row]=av.y; As[kc+2][row]=av.z; As[kc+3][row]=av.w;
    int bk = tid >> 4, c0 = (tid & 15) << 2;
#pragma unroll
    for (int jj = 0; jj < 4; ++jj){
      int c = bn*64 + c0 + jj;
      Bs[bk][c0+jj] = (c < OD) ? Wp[(size_t)(kt+bk)*OD + c] : 0.0f;
    }
    __syncthreads();
#pragma unroll
    for (int kk = 0; kk < 16; ++kk){
      float4 a = *(const float4*)&As[kk][ty*4];
      float4 b = *(const float4*)&Bs[kk][tx*4];
      float aa[4]={a.x,a.y,a.z,a.w}, bb[4]={b.x,b.y,b.z,b.w};
#pragma unroll
      for (int ii=0; ii<4; ++ii)
#pragma unroll
        for (int jj=0; jj<4; ++jj) acc[ii][jj] += aa[ii]*bb[jj];
    }
    __syncthreads();
  }
#pragma unroll
  for (int ii=0; ii<4; ++ii){
    int r = bm*64 + ty*4 + ii;
#pragma unroll
    for (int jj=0; jj<4; ++jj){
      int c = bn*64 + tx*4 + jj;
      if (c < OD) out[(size_t)r*OD + c] = acc[ii][jj] + bp[c];
    }
  }
}

extern "C" void kernel_launch(void* const* d_in, const int* in_sizes, int n_in,
                              void* d_out, int out_size, void* d_ws, size_t ws_size,
                              hipStream_t stream){
  const float* fq = (const float*)d_in[0];
  const float* fk = (const float*)d_in[1];
  const float* fv = (const float*)d_in[2];
  const float* GA = (const float*)d_in[3];
  const float* GB = (const float*)d_in[4];
  const float* Wp = (const float*)d_in[5];
  const float* bp = (const float*)d_in[6];
  float* out  = (float*)d_out;
  float* attn = out + (size_t)S*OD;

  float* ws     = (float*)d_ws;
  float* QT     = ws;                                // 129*16384
  float* g      = QT + (size_t)129*N*N;              // 128*128
  float* bounds = g + (size_t)L*N;                   // 65*3*128
  float* cs     = bounds + (size_t)(NC+1)*3*N;       // 3*8192*128
  float* ctx    = cs + (size_t)3*S*N;                // 8192*128
  u16*   qkh    = (u16*)(ctx + (size_t)S*N);         // 2*S*N u16
  u16*   qkl    = qkh + (size_t)2*S*N;               // 2*S*N u16
  u16*   vth    = qkl + (size_t)2*S*N;               // S*N u16 ([N][S])
  u16*   vtl    = vth + (size_t)S*N;                 // S*N u16
  float* pmax   = (float*)(vtl + (size_t)S*N);       // 64*8192
  float* psum   = pmax + (size_t)(S/128)*S;          // 64*8192
  float* rowm   = psum + (size_t)(S/128)*S;          // 8192
  float* rowinv = rowm + S;                          // 8192
  float* part   = rowinv + S;                        // KSPLIT*8192*128 (optional)
  size_t need_part = ((size_t)(part - ws) + (size_t)KSPLIT*S*N) * sizeof(float);
  bool use_part = (ws_size >= need_part);

  k_copyT<<<64, 256, 0, stream>>>(GA, QT + (size_t)N*N);
  for (int m = 1; m < L; m <<= 1)
    k_powmm<<<dim3(2,2,m), dim3(16,16), 0, stream>>>(QT, m);
  k_g<<<128, 128, 0, stream>>>(QT, GB, g);
  k_fill_local<<<dim3(4,3,NC), dim3(16,16), 0, stream>>>(fq, fk, fv, g, cs);
  k_bscan<<<1, 384, 0, stream>>>(QT, cs, bounds);
  k_fill_bound<<<dim3(L,4), 256, 0, stream>>>(QT, bounds, cs);

  k_split_qk<<<(2*S*N)/1024, 256, 0, stream>>>(cs, qkh, qkl);
  k_split_vT<<<S/64, 256, 0, stream>>>(cs + (size_t)2*S*N, vth, vtl);

  k_score_mfma<<<dim3(S/128, S/128), 256, 0, stream>>>(
      qkh, qkl, qkh + (size_t)S*N, qkl + (size_t)S*N, attn, pmax, psum);
  k_rowstat<<<S/256, 256, 0, stream>>>(pmax, psum, rowm, rowinv);
  if (use_part){
    k_context_mfma<<<dim3(KSPLIT, S/128), 256, 0, stream>>>(attn, rowm, rowinv, vth, vtl, part, 0);
    k_reduce<<<(S*N/4)/256, 256, 0, stream>>>(part, ctx);
  } else {
    hipMemsetAsync(ctx, 0, (size_t)S*N*sizeof(float), stream);
    k_context_mfma<<<dim3(KSPLIT, S/128), 256, 0, stream>>>(attn, rowm, rowinv, vth, vtl, ctx, 1);
  }
  k_out<<<dim3(16, S/64), dim3(16,16), 0, stream>>>(ctx, Wp, bp, out);
}

// Round 4
// 896.816 us; speedup vs baseline: 1.0937x; 1.0937x over previous
//
#include <hip/hip_runtime.h>

static constexpr int N  = 128;   // N_STATE
static constexpr int S  = 8192;  // SEQ
static constexpr int L  = 128;   // chunk length
static constexpr int NC = 64;    // S/L
static constexpr int OD = 1000;  // OUT_DIM
static constexpr int KSPLIT = 16;
#define SCL 0.25f                // 1/sqrt(D_HEAD=16), exact power of 2

typedef unsigned short u16;
typedef __attribute__((ext_vector_type(4))) unsigned short us4;
typedef __attribute__((ext_vector_type(8))) unsigned short us8;
typedef __attribute__((ext_vector_type(8))) short bf16x8;   // 8 bf16 = 4 VGPRs
typedef __attribute__((ext_vector_type(4))) float f32x4;

__device__ __forceinline__ u16 f2bf(float x){
  unsigned u = __float_as_uint(x);
  u += 0x7FFFu + ((u >> 16) & 1u);   // RNE to bf16
  return (u16)(u >> 16);
}
__device__ __forceinline__ float bf2f(u16 h){
  return __uint_as_float(((unsigned)h) << 16);
}

// ---- QT[1] = GA^T ----
__global__ void k_copyT(const float* __restrict__ GA, float* __restrict__ QT1){
  int idx = blockIdx.x*256 + threadIdx.x;
  int m = idx >> 7, n = idx & 127;
  QT1[idx] = GA[n*N + m];
}

// ---- QT[mlev+i] = QT[mlev] @ QT[i] ----
__global__ __launch_bounds__(256) void k_powmm(float* QT, int mlev){
  int i = blockIdx.z + 1;
  const float* Am = QT + (size_t)mlev*(N*N);
  const float* Ai = QT + (size_t)i*(N*N);
  float* C = QT + (size_t)(mlev+i)*(N*N);
  __shared__ __align__(16) float As[16][68];
  __shared__ __align__(16) float Bs[16][68];
  int bm = blockIdx.y, bn = blockIdx.x;
  int tx = threadIdx.x, ty = threadIdx.y;
  int tid = ty*16 + tx;
  float acc[4][4] = {};
  for (int kt = 0; kt < N; kt += 16){
    int row = tid >> 2, kc = (tid & 3) << 2;
    float4 av = *(const float4*)(Am + (size_t)(bm*64+row)*N + kt + kc);
    As[kc+0][row]=av.x; As[kc+1][row]=av.y; As[kc+2][row]=av.z; As[kc+3][row]=av.w;
    int bk = tid >> 4, c0 = (tid & 15) << 2;
    *(float4*)&Bs[bk][c0] = *(const float4*)(Ai + (size_t)(kt+bk)*N + bn*64 + c0);
    __syncthreads();
#pragma unroll
    for (int kk = 0; kk < 16; ++kk){
      float4 a = *(const float4*)&As[kk][ty*4];
      float4 b = *(const float4*)&Bs[kk][tx*4];
      float aa[4]={a.x,a.y,a.z,a.w}, bb[4]={b.x,b.y,b.z,b.w};
#pragma unroll
      for (int ii=0; ii<4; ++ii)
#pragma unroll
        for (int jj=0; jj<4; ++jj) acc[ii][jj] += aa[ii]*bb[jj];
    }
    __syncthreads();
  }
#pragma unroll
  for (int ii=0; ii<4; ++ii){
    float4 vst = make_float4(acc[ii][0],acc[ii][1],acc[ii][2],acc[ii][3]);
    *(float4*)(C + (size_t)(bm*64+ty*4+ii)*N + bn*64 + tx*4) = vst;
  }
}

// ---- g[k] = GA^k GB ----
__global__ void k_g(const float* __restrict__ QT, const float* __restrict__ GB,
                    float* __restrict__ g){
  int kb = blockIdx.x;
  int n = threadIdx.x;
  if (kb == 0){ g[n] = GB[n]; return; }
  const float* Qk = QT + (size_t)kb*(N*N);
  float acc = 0.0f;
  for (int m = 0; m < N; ++m) acc += Qk[m*N + n]*GB[m];
  g[kb*N + n] = acc;
}

// ---- within-chunk causal conv ----
__global__ __launch_bounds__(256) void k_fill_local(const float* __restrict__ fq,
                             const float* __restrict__ fk, const float* __restrict__ fv,
                             const float* __restrict__ g, float* __restrict__ cs){
  int tile = blockIdx.x;
  int s = blockIdx.y, j = blockIdx.z;
  const float* f = (s==0)? fq : (s==1)? fk : fv;
  __shared__ float flp[256];
  __shared__ __align__(16) float Bs[16][68];
  int tx = threadIdx.x, ty = threadIdx.y;
  int tid = ty*16 + tx;
  flp[tid] = (tid < 128) ? 0.0f : f[j*L + tid - 128];
  int ti = tile >> 1, tj = tile & 1;
  float acc[4][4] = {};
  int kmax = (ti == 0) ? 64 : 128;
  for (int kt = 0; kt < kmax; kt += 16){
    int bk = tid >> 4, c0 = (tid & 15) << 2;
    *(float4*)&Bs[bk][c0] = *(const float4*)(g + (size_t)(kt+bk)*N + tj*64 + c0);
    __syncthreads();
#pragma unroll
    for (int kk = 0; kk < 16; ++kk){
      float4 b = *(const float4*)&Bs[kk][tx*4];
      int base = 128 + ti*64 + ty*4 - kt - kk;
      float aa[4] = {flp[base], flp[base+1], flp[base+2], flp[base+3]};
      float bb[4] = {b.x, b.y, b.z, b.w};
#pragma unroll
      for (int ii=0; ii<4; ++ii)
#pragma unroll
        for (int jj=0; jj<4; ++jj) acc[ii][jj] += aa[ii]*bb[jj];
    }
    __syncthreads();
  }
#pragma unroll
  for (int ii=0; ii<4; ++ii){
    int row = ti*64 + ty*4 + ii;
    float4 vst = make_float4(acc[ii][0],acc[ii][1],acc[ii][2],acc[ii][3]);
    *(float4*)(cs + ((size_t)s*S + (size_t)j*L + row)*N + tj*64 + tx*4) = vst;
  }
}

// ---- sequential chunk-boundary scan ----
__global__ void k_bscan(const float* __restrict__ QT, const float* __restrict__ cs,
                        float* __restrict__ bounds){
  __shared__ float bc[3][N];
  __shared__ float bnx[3][N];
  int tid = threadIdx.x;
  int s = tid >> 7, n = tid & 127;
  const float* QL = QT + (size_t)L*(N*N);
  bc[s][n] = 0.0f;
  bounds[(0*3+s)*N + n] = 0.0f;
  __syncthreads();
  for (int j = 0; j < NC; ++j){
    float acc = cs[((size_t)s*S + (size_t)j*L + 127)*N + n];
    for (int m = 0; m < N; ++m) acc += QL[m*N+n]*bc[s][m];
    bnx[s][n] = acc;
    bounds[((j+1)*3+s)*N + n] = acc;
    __syncthreads();
    bc[s][n] = bnx[s][n];
    __syncthreads();
  }
}

// ---- boundary fill: cs[s][jL+i] += GA^{i+1} b_j  (4-task register blocking) ----
__global__ __launch_bounds__(256) void k_fill_bound(const float* __restrict__ QT,
                          const float* __restrict__ bounds, float* __restrict__ cs){
  int i = blockIdx.x;
  int jg = blockIdx.y;
  __shared__ float Qs[N*N];
  int tid = threadIdx.x;
  int p = tid >> 7, n = tid & 127;
  const float* Qg = QT + (size_t)(i+1)*(N*N);
  for (int idx = tid; idx < N*N; idx += 256) Qs[idx] = Qg[idx];
  __syncthreads();
  for (int r4 = 0; r4 < 24; r4 += 4){
    int task0 = jg*48 + p*24 + r4;
    const float* b0 = bounds + (size_t)task0*N;
    const float* b1 = b0 + N;
    const float* b2 = b0 + 2*N;
    const float* b3 = b0 + 3*N;
    float a0=0.f, a1=0.f, a2=0.f, a3=0.f;
#pragma unroll 4
    for (int m = 0; m < N; ++m){
      float q = Qs[m*N + n];
      a0 += q*b0[m]; a1 += q*b1[m]; a2 += q*b2[m]; a3 += q*b3[m];
    }
    float av[4] = {a0, a1, a2, a3};
#pragma unroll
    for (int q4 = 0; q4 < 4; ++q4){
      int task = task0 + q4;
      int j = task/3, s2 = task - 3*j;
      cs[((size_t)s2*S + (size_t)j*L + i)*N + n] += av[q4];
    }
  }
}

// ---- split q,k states into bf16 hi/lo (natural [2*S][N] layout) ----
__global__ void k_split_qk(const float* __restrict__ cs,
                           u16* __restrict__ sh, u16* __restrict__ sl){
  size_t i = ((size_t)blockIdx.x*256 + threadIdx.x) << 2;
  float4 v = *(const float4*)(cs + i);
  us4 h, l;
  h[0]=f2bf(v.x); l[0]=f2bf(v.x - bf2f(h[0]));
  h[1]=f2bf(v.y); l[1]=f2bf(v.y - bf2f(h[1]));
  h[2]=f2bf(v.z); l[2]=f2bf(v.z - bf2f(h[2]));
  h[3]=f2bf(v.w); l[3]=f2bf(v.w - bf2f(h[3]));
  *(us4*)(sh + i) = h;
  *(us4*)(sl + i) = l;
}

// ---- split v states into bf16 hi/lo, k-tiled transpose: [S/32][128][32] ----
__global__ __launch_bounds__(256) void k_split_vT(const float* __restrict__ vs,
                           u16* __restrict__ vth, u16* __restrict__ vtl){
  __shared__ u16 Th[128*72];
  __shared__ u16 Tl[128*72];
  int t0 = blockIdx.x * 64;
  int tid = threadIdx.x;
  for (int c = tid; c < 2048; c += 256){
    int i = c >> 5, n0 = (c & 31) << 2;
    float4 v = *(const float4*)(vs + (size_t)(t0 + i)*N + n0);
    u16 h;
    h = f2bf(v.x); Th[(n0+0)*72 + i] = h; Tl[(n0+0)*72 + i] = f2bf(v.x - bf2f(h));
    h = f2bf(v.y); Th[(n0+1)*72 + i] = h; Tl[(n0+1)*72 + i] = f2bf(v.y - bf2f(h));
    h = f2bf(v.z); Th[(n0+2)*72 + i] = h; Tl[(n0+2)*72 + i] = f2bf(v.z - bf2f(h));
    h = f2bf(v.w); Th[(n0+3)*72 + i] = h; Tl[(n0+3)*72 + i] = f2bf(v.w - bf2f(h));
  }
  __syncthreads();
  for (int c = tid; c < 1024; c += 256){
    int n = c >> 3, tc = (c & 7) << 3;
    int tile = (t0 + tc) >> 5;
    int kin  = (t0 + tc) & 31;
    size_t dst = (size_t)tile*4096 + n*32 + kin;
    *(us8*)(vth + dst) = *(const us8*)&Th[n*72 + tc];
    *(us8*)(vtl + dst) = *(const us8*)&Tl[n*72 + tc];
  }
}

// ---- stats-only QK^T (swapped: S^T = K @ Q^T), per-(col-block,row) max/sumexp ----
__global__ __launch_bounds__(256) void k_stats(
    const u16* __restrict__ qh, const u16* __restrict__ ql,
    const u16* __restrict__ kh, const u16* __restrict__ kl,
    float* __restrict__ pmax, float* __restrict__ psum){
  __shared__ __align__(16) u16 Ah[128*40], Al[128*40], Bh[128*40], Bl[128*40];
  __shared__ float wst[2][128][2];
  int bm = blockIdx.y, bn = blockIdx.x;
  int tid = threadIdx.x;
  int lane = tid & 63, w = tid >> 6;
  int l15 = lane & 15, l4 = lane >> 4;
  int wr = w >> 1, wc = w & 1;          // wr: seq-half, wc: q-half
  int kg = l4 << 3;
  f32x4 accs[4][4] = {};                // [si(seq)][qi(q)]
  for (int kt = 0; kt < N; kt += 32){
    for (int c = tid; c < 512; c += 256){
      int r = c >> 2, k8 = (c & 3) << 3;
      size_t ga = (size_t)(bm*128 + r)*N + kt + k8;   // q rows
      size_t gb = (size_t)(bn*128 + r)*N + kt + k8;   // k rows (seq)
      int lo = r*40 + k8;
      *(us8*)&Ah[lo] = *(const us8*)(qh + ga);
      *(us8*)&Al[lo] = *(const us8*)(ql + ga);
      *(us8*)&Bh[lo] = *(const us8*)(kh + gb);
      *(us8*)&Bl[lo] = *(const us8*)(kl + gb);
    }
    __syncthreads();
    bf16x8 kfh[4], kfl[4], qfh[4], qfl[4];
#pragma unroll
    for (int si = 0; si < 4; ++si){
      kfh[si] = *(const bf16x8*)&Bh[(wr*64 + si*16 + l15)*40 + kg];
      kfl[si] = *(const bf16x8*)&Bl[(wr*64 + si*16 + l15)*40 + kg];
    }
#pragma unroll
    for (int qi = 0; qi < 4; ++qi){
      qfh[qi] = *(const bf16x8*)&Ah[(wc*64 + qi*16 + l15)*40 + kg];
      qfl[qi] = *(const bf16x8*)&Al[(wc*64 + qi*16 + l15)*40 + kg];
    }
#pragma unroll
    for (int si = 0; si < 4; ++si)
#pragma unroll
      for (int qi = 0; qi < 4; ++qi){
        accs[si][qi] = __builtin_amdgcn_mfma_f32_16x16x32_bf16(kfh[si], qfh[qi], accs[si][qi], 0,0,0);
        accs[si][qi] = __builtin_amdgcn_mfma_f32_16x16x32_bf16(kfh[si], qfl[qi], accs[si][qi], 0,0,0);
        accs[si][qi] = __builtin_amdgcn_mfma_f32_16x16x32_bf16(kfl[si], qfh[qi], accs[si][qi], 0,0,0);
      }
    __syncthreads();
  }
  // per-q stats over this wave's 64 seq: reduce (si,r) in-lane, l4 via shuffle
  float mq[4], sq[4];
#pragma unroll
  for (int qi = 0; qi < 4; ++qi){
    float m = -3.0e38f;
#pragma unroll
    for (int si = 0; si < 4; ++si)
#pragma unroll
      for (int r = 0; r < 4; ++r) m = fmaxf(m, accs[si][qi][r]);
    mq[qi] = m * SCL;   // SCL = 2^-2: exact, commutes with max
  }
#pragma unroll
  for (int qi = 0; qi < 4; ++qi){
    mq[qi] = fmaxf(mq[qi], __shfl_xor(mq[qi], 16, 64));
    mq[qi] = fmaxf(mq[qi], __shfl_xor(mq[qi], 32, 64));
  }
#pragma unroll
  for (int qi = 0; qi < 4; ++qi){
    float s = 0.0f;
#pragma unroll
    for (int si = 0; si < 4; ++si)
#pragma unroll
      for (int r = 0; r < 4; ++r) s += __expf(accs[si][qi][r]*SCL - mq[qi]);
    sq[qi] = s;
  }
#pragma unroll
  for (int qi = 0; qi < 4; ++qi){
    sq[qi] += __shfl_xor(sq[qi], 16, 64);
    sq[qi] += __shfl_xor(sq[qi], 32, 64);
  }
  if (l4 == 0){
#pragma unroll
    for (int qi = 0; qi < 4; ++qi){
      int ql_ = wc*64 + qi*16 + l15;
      wst[wr][ql_][0] = mq[qi];
      wst[wr][ql_][1] = sq[qi];
    }
  }
  __syncthreads();
  if (tid < 128){
    float m0 = wst[0][tid][0], m1 = wst[1][tid][0];
    float m = fmaxf(m0, m1);
    float Z = wst[0][tid][1]*__expf(m0 - m) + wst[1][tid][1]*__expf(m1 - m);
    pmax[(size_t)bn*S + bm*128 + tid] = m;
    psum[(size_t)bn*S + bm*128 + tid] = Z;
  }
}

// ---- merge per-col-block partials -> per-row (max, 1/Z) ----
__global__ void k_rowstat(const float* __restrict__ pmax, const float* __restrict__ psum,
                          float* __restrict__ rowm, float* __restrict__ rowinv){
  int t = blockIdx.x*256 + threadIdx.x;
  float m = -3.0e38f;
  for (int b = 0; b < 64; ++b) m = fmaxf(m, pmax[(size_t)b*S + t]);
  float Z = 0.0f;
  for (int b = 0; b < 64; ++b) Z += psum[(size_t)b*S + t]*__expf(pmax[(size_t)b*S + t] - m);
  rowm[t] = m;
  rowinv[t] = 1.0f/Z;
}

// ---- fused: recompute S^T, normalize, write attn (once), PV via zero-pad MFMA ----
// Wave w owns 32 q-rows. S^T = mfma(K,Q): lane holds p for q=qi*16+(lane&15),
// seq=si*16+(lane>>4)*4+r -> float4 attn stores + lane-local PV A-fragments
// (p in A slots j=0..3 of k=8*(lane>>4)+j, slots j>=4 zero; V staged to match).
__global__ __launch_bounds__(256) void k_ctx(
    float* __restrict__ attn,
    const float* __restrict__ rowm, const float* __restrict__ rowinv,
    const u16* __restrict__ qh, const u16* __restrict__ ql,
    const u16* __restrict__ kh, const u16* __restrict__ kl,
    const u16* __restrict__ vth, const u16* __restrict__ vtl,  // [S/32][128][32]
    float* __restrict__ dst, int mode){
  __shared__ __align__(16) u16 Ksh[32*136], Ksl[32*136];  // seq-major K tile
  __shared__ __align__(16) u16 Vsh[128*40], Vsl[128*40];  // [n][k32] tile
  int bm = blockIdx.x, kz = blockIdx.y;   // consecutive blocks share kz's K/V slice
  int tid = threadIdx.x, lane = tid & 63, w = tid >> 6;
  int l15 = lane & 15, l4 = lane >> 4;
  int kg = l4 << 3;
  const int KC = S / KSPLIT;   // 512
  int k0 = kz*KC;
  int qrow0 = bm*128 + w*32;
  // Q fragments (held whole kernel) + row stats
  bf16x8 qfh[2][4], qfl[2][4];
  float rm[2], ri[2];
#pragma unroll
  for (int qi = 0; qi < 2; ++qi){
    int q = qrow0 + qi*16 + l15;
#pragma unroll
    for (int kt = 0; kt < 4; ++kt){
      qfh[qi][kt] = *(const bf16x8*)(qh + (size_t)q*N + kt*32 + kg);
      qfl[qi][kt] = *(const bf16x8*)(ql + (size_t)q*N + kt*32 + kg);
    }
    rm[qi] = rowm[q];
    ri[qi] = rowinv[q];
  }
  f32x4 acco[2][8] = {};   // [qi][ni] out accumulator (q x n)
  for (int ko = 0; ko < KC/32; ++ko){
    int cb = k0 + ko*32;
    // stage K tile (32 seq x 128 n, hi/lo)
    for (int c = tid; c < 512; c += 256){
      int rr = c >> 4, k8 = (c & 15) << 3;
      size_t gk = (size_t)(cb + rr)*N + k8;
      *(us8*)&Ksh[rr*136 + k8] = *(const us8*)(kh + gk);
      *(us8*)&Ksl[rr*136 + k8] = *(const us8*)(kl + gk);
    }
    // stage V tile (contiguous 8KB per array)
    {
      const u16* sh = vth + (size_t)(cb >> 5)*4096;
      const u16* sl = vtl + (size_t)(cb >> 5)*4096;
      for (int c = tid; c < 512; c += 256){
        int n = c >> 2, k8 = (c & 3) << 3;
        *(us8*)&Vsh[n*40 + k8] = *(const us8*)(sh + (size_t)c*8);
        *(us8*)&Vsl[n*40 + k8] = *(const us8*)(sl + (size_t)c*8);
      }
    }
    __syncthreads();
    // S^T tile: accs[si][qi], K from LDS, Q from regs (same order as k_stats)
    f32x4 accs[2][2] = {};
#pragma unroll
    for (int kt = 0; kt < 4; ++kt){
      bf16x8 kfh[2], kfl[2];
#pragma unroll
      for (int si = 0; si < 2; ++si){
        kfh[si] = *(const bf16x8*)&Ksh[(si*16 + l15)*136 + kt*32 + kg];
        kfl[si] = *(const bf16x8*)&Ksl[(si*16 + l15)*136 + kt*32 + kg];
      }
#pragma unroll
      for (int si = 0; si < 2; ++si)
#pragma unroll
        for (int qi = 0; qi < 2; ++qi){
          accs[si][qi] = __builtin_amdgcn_mfma_f32_16x16x32_bf16(kfh[si], qfh[qi][kt], accs[si][qi], 0,0,0);
          accs[si][qi] = __builtin_amdgcn_mfma_f32_16x16x32_bf16(kfh[si], qfl[qi][kt], accs[si][qi], 0,0,0);
          accs[si][qi] = __builtin_amdgcn_mfma_f32_16x16x32_bf16(kfl[si], qfh[qi][kt], accs[si][qi], 0,0,0);
        }
    }
    // normalize + attn store (float4 over r) + lane-local p fragments
    bf16x8 pah[2][2], pal[2][2];   // [si][qi], high 4 slots zero
#pragma unroll
    for (int si = 0; si < 2; ++si)
#pragma unroll
      for (int qi = 0; qi < 2; ++qi){
        float p0 = __expf(accs[si][qi][0]*SCL - rm[qi]) * ri[qi];
        float p1 = __expf(accs[si][qi][1]*SCL - rm[qi]) * ri[qi];
        float p2 = __expf(accs[si][qi][2]*SCL - rm[qi]) * ri[qi];
        float p3 = __expf(accs[si][qi][3]*SCL - rm[qi]) * ri[qi];
        int q = qrow0 + qi*16 + l15;
        *(float4*)(attn + (size_t)q*S + cb + si*16 + (l4<<2)) = make_float4(p0,p1,p2,p3);
        u16 h0=f2bf(p0), h1=f2bf(p1), h2=f2bf(p2), h3=f2bf(p3);
        u16 e0=f2bf(p0-bf2f(h0)), e1=f2bf(p1-bf2f(h1)), e2=f2bf(p2-bf2f(h2)), e3=f2bf(p3-bf2f(h3));
        bf16x8 ah; ah[0]=(short)h0; ah[1]=(short)h1; ah[2]=(short)h2; ah[3]=(short)h3;
        ah[4]=0; ah[5]=0; ah[6]=0; ah[7]=0;
        bf16x8 al; al[0]=(short)e0; al[1]=(short)e1; al[2]=(short)e2; al[3]=(short)e3;
        al[4]=0; al[5]=0; al[6]=0; al[7]=0;
        pah[si][qi] = ah; pal[si][qi] = al;
      }
    // PV: half-K MFMAs, V slots j<4 = V[si*16+4*l4+j], j>=4 zero (x0 in A anyway)
#pragma unroll
    for (int si = 0; si < 2; ++si)
#pragma unroll
      for (int ni = 0; ni < 8; ++ni){
        int vaddr = (ni*16 + l15)*40 + si*16 + (l4<<2);
        us4 vh4 = *(const us4*)&Vsh[vaddr];
        us4 vl4 = *(const us4*)&Vsl[vaddr];
        bf16x8 vh; vh[0]=(short)vh4[0]; vh[1]=(short)vh4[1]; vh[2]=(short)vh4[2]; vh[3]=(short)vh4[3];
        vh[4]=0; vh[5]=0; vh[6]=0; vh[7]=0;
        bf16x8 vl; vl[0]=(short)vl4[0]; vl[1]=(short)vl4[1]; vl[2]=(short)vl4[2]; vl[3]=(short)vl4[3];
        vl[4]=0; vl[5]=0; vl[6]=0; vl[7]=0;
#pragma unroll
        for (int qi = 0; qi < 2; ++qi){
          acco[qi][ni] = __builtin_amdgcn_mfma_f32_16x16x32_bf16(pah[si][qi], vh, acco[qi][ni], 0,0,0);
          acco[qi][ni] = __builtin_amdgcn_mfma_f32_16x16x32_bf16(pah[si][qi], vl, acco[qi][ni], 0,0,0);
          acco[qi][ni] = __builtin_amdgcn_mfma_f32_16x16x32_bf16(pal[si][qi], vh, acco[qi][ni], 0,0,0);
        }
      }
    __syncthreads();   // before next iter's staging overwrites K/V
  }
  // epilogue: out rows q = qrow0 + qi*16 + (l4<<2)+r, cols n = ni*16 + l15
  if (mode == 0){
    float* P = dst + (size_t)kz*S*N;
#pragma unroll
    for (int qi = 0; qi < 2; ++qi)
#pragma unroll
      for (int ni = 0; ni < 8; ++ni)
#pragma unroll
        for (int r = 0; r < 4; ++r){
          int q = qrow0 + qi*16 + (l4<<2) + r;
          P[(size_t)q*N + ni*16 + l15] = acco[qi][ni][r];
        }
  } else {
#pragma unroll
    for (int qi = 0; qi < 2; ++qi)
#pragma unroll
      for (int ni = 0; ni < 8; ++ni)
#pragma unroll
        for (int r = 0; r < 4; ++r){
          int q = qrow0 + qi*16 + (l4<<2) + r;
          atomicAdd(&dst[(size_t)q*N + ni*16 + l15], acco[qi][ni][r]);
        }
  }
}

// ---- reduce partials -> ctx ----
__global__ __launch_bounds__(256) void k_reduce(const float* __restrict__ part,
                                                float* __restrict__ ctx){
  size_t idx = (size_t)blockIdx.x*256 + threadIdx.x;
  const float4* p4 = (const float4*)part;
  float4 acc = p4[idx];
  const size_t stride = (size_t)S*N/4;
#pragma unroll
  for (int kz = 1; kz < KSPLIT; ++kz){
    float4 v = p4[(size_t)kz*stride + idx];
    acc.x += v.x; acc.y += v.y; acc.z += v.z; acc.w += v.w;
  }
  ((float4*)ctx)[idx] = acc;
}

// ---- out = ctx @ Wp + bp ----
__global__ __launch_bounds__(256) void k_out(const float* __restrict__ ctx,
                   const float* __restrict__ Wp, const float* __restrict__ bp,
                   float* __restrict__ out){
  __shared__ __align__(16) float As[16][68];
  __shared__ __align__(16) float Bs[16][68];
  int bn = blockIdx.x;
  int bm = blockIdx.y;
  int tx = threadIdx.x, ty = threadIdx.y;
  int tid = ty*16 + tx;
  float acc[4][4] = {};
  for (int kt = 0; kt < N; kt += 16){
    int row = tid >> 2, kc = (tid & 3) << 2;
    float4 av = *(const float4*)(ctx + (size_t)(bm*64+row)*N + kt + kc);
    As[kc+0][row]=av.x; As[kc+1][row]=av.y; As[kc+2][row]=av.z; As[kc+3][row]=av.w;
    int bk = tid >> 4, c0 = (tid & 15) << 2;
#pragma unroll
    for (int jj = 0; jj < 4; ++jj){
      int c = bn*64 + c0 + jj;
      Bs[bk][c0+jj] = (c < OD) ? Wp[(size_t)(kt+bk)*OD + c] : 0.0f;
    }
    __syncthreads();
#pragma unroll
    for (int kk = 0; kk < 16; ++kk){
      float4 a = *(const float4*)&As[kk][ty*4];
      float4 b = *(const float4*)&Bs[kk][tx*4];
      float aa[4]={a.x,a.y,a.z,a.w}, bb[4]={b.x,b.y,b.z,b.w};
#pragma unroll
      for (int ii=0; ii<4; ++ii)
#pragma unroll
        for (int jj=0; jj<4; ++jj) acc[ii][jj] += aa[ii]*bb[jj];
    }
    __syncthreads();
  }
#pragma unroll
  for (int ii=0; ii<4; ++ii){
    int r = bm*64 + ty*4 + ii;
#pragma unroll
    for (int jj=0; jj<4; ++jj){
      int c = bn*64 + tx*4 + jj;
      if (c < OD) out[(size_t)r*OD + c] = acc[ii][jj] + bp[c];
    }
  }
}

extern "C" void kernel_launch(void* const* d_in, const int* in_sizes, int n_in,
                              void* d_out, int out_size, void* d_ws, size_t ws_size,
                              hipStream_t stream){
  const float* fq = (const float*)d_in[0];
  const float* fk = (const float*)d_in[1];
  const float* fv = (const float*)d_in[2];
  const float* GA = (const float*)d_in[3];
  const float* GB = (const float*)d_in[4];
  const float* Wp = (const float*)d_in[5];
  const float* bp = (const float*)d_in[6];
  float* out  = (float*)d_out;
  float* attn = out + (size_t)S*OD;

  float* ws     = (float*)d_ws;
  float* QT     = ws;                                // 129*16384
  float* g      = QT + (size_t)129*N*N;              // 128*128
  float* bounds = g + (size_t)L*N;                   // 65*3*128
  float* cs     = bounds + (size_t)(NC+1)*3*N;       // 3*8192*128
  float* ctx    = cs + (size_t)3*S*N;                // 8192*128
  u16*   qkh    = (u16*)(ctx + (size_t)S*N);         // 2*S*N u16
  u16*   qkl    = qkh + (size_t)2*S*N;               // 2*S*N u16
  u16*   vth    = qkl + (size_t)2*S*N;               // S*N u16 tiled [S/32][128][32]
  u16*   vtl    = vth + (size_t)S*N;                 // S*N u16
  float* pmax   = (float*)(vtl + (size_t)S*N);       // 64*8192
  float* psum   = pmax + (size_t)(S/128)*S;          // 64*8192
  float* rowm   = psum + (size_t)(S/128)*S;          // 8192
  float* rowinv = rowm + S;                          // 8192
  float* part   = rowinv + S;                        // KSPLIT*8192*128 (optional)
  size_t need_part = ((size_t)(part - ws) + (size_t)KSPLIT*S*N) * sizeof(float);
  bool use_part = (ws_size >= need_part);

  k_copyT<<<64, 256, 0, stream>>>(GA, QT + (size_t)N*N);
  for (int m = 1; m < L; m <<= 1)
    k_powmm<<<dim3(2,2,m), dim3(16,16), 0, stream>>>(QT, m);
  k_g<<<128, 128, 0, stream>>>(QT, GB, g);
  k_fill_local<<<dim3(4,3,NC), dim3(16,16), 0, stream>>>(fq, fk, fv, g, cs);
  k_bscan<<<1, 384, 0, stream>>>(QT, cs, bounds);
  k_fill_bound<<<dim3(L,4), 256, 0, stream>>>(QT, bounds, cs);

  k_split_qk<<<(2*S*N)/1024, 256, 0, stream>>>(cs, qkh, qkl);
  k_split_vT<<<S/64, 256, 0, stream>>>(cs + (size_t)2*S*N, vth, vtl);

  k_stats<<<dim3(S/128, S/128), 256, 0, stream>>>(
      qkh, qkl, qkh + (size_t)S*N, qkl + (size_t)S*N, pmax, psum);
  k_rowstat<<<S/256, 256, 0, stream>>>(pmax, psum, rowm, rowinv);
  if (use_part){
    k_ctx<<<dim3(S/128, KSPLIT), 256, 0, stream>>>(attn, rowm, rowinv,
        qkh, qkl, qkh + (size_t)S*N, qkl + (size_t)S*N, vth, vtl, part, 0);
    k_reduce<<<(S*N/4)/256, 256, 0, stream>>>(part, ctx);
  } else {
    hipMemsetAsync(ctx, 0, (size_t)S*N*sizeof(float), stream);
    k_ctx<<<dim3(S/128, KSPLIT), 256, 0, stream>>>(attn, rowm, rowinv,
        qkh, qkl, qkh + (size_t)S*N, qkl + (size_t)S*N, vth, vtl, ctx, 1);
  }
  k_out<<<dim3(16, S/64), dim3(16,16), 0, stream>>>(ctx, Wp, bp, out);
}

// Round 5
// 895.705 us; speedup vs baseline: 1.0950x; 1.0012x over previous
//
#include <hip/hip_runtime.h>

static constexpr int N  = 128;   // N_STATE
static constexpr int S  = 8192;  // SEQ
static constexpr int L  = 128;   // chunk length
static constexpr int NC = 64;    // S/L
static constexpr int OD = 1000;  // OUT_DIM
static constexpr int KSPLIT = 16;
#define SCL 0.25f                // 1/sqrt(D_HEAD=16), exact power of 2

typedef unsigned short u16;
typedef __attribute__((ext_vector_type(4))) unsigned short us4;
typedef __attribute__((ext_vector_type(8))) unsigned short us8;
typedef __attribute__((ext_vector_type(8))) short bf16x8;   // 8 bf16 = 4 VGPRs
typedef __attribute__((ext_vector_type(4))) float f32x4;

__device__ __forceinline__ u16 f2bf(float x){
  unsigned u = __float_as_uint(x);
  u += 0x7FFFu + ((u >> 16) & 1u);   // RNE to bf16
  return (u16)(u >> 16);
}
__device__ __forceinline__ float bf2f(u16 h){
  return __uint_as_float(((unsigned)h) << 16);
}

// ---- QT[1] = GA^T ----
__global__ void k_copyT(const float* __restrict__ GA, float* __restrict__ QT1){
  int idx = blockIdx.x*256 + threadIdx.x;
  int m = idx >> 7, n = idx & 127;
  QT1[idx] = GA[n*N + m];
}

// ---- QT[mlev+i] = QT[mlev] @ QT[i] ----
__global__ __launch_bounds__(256) void k_powmm(float* QT, int mlev){
  int i = blockIdx.z + 1;
  const float* Am = QT + (size_t)mlev*(N*N);
  const float* Ai = QT + (size_t)i*(N*N);
  float* C = QT + (size_t)(mlev+i)*(N*N);
  __shared__ __align__(16) float As[16][68];
  __shared__ __align__(16) float Bs[16][68];
  int bm = blockIdx.y, bn = blockIdx.x;
  int tx = threadIdx.x, ty = threadIdx.y;
  int tid = ty*16 + tx;
  float acc[4][4] = {};
  for (int kt = 0; kt < N; kt += 16){
    int row = tid >> 2, kc = (tid & 3) << 2;
    float4 av = *(const float4*)(Am + (size_t)(bm*64+row)*N + kt + kc);
    As[kc+0][row]=av.x; As[kc+1][row]=av.y; As[kc+2][row]=av.z; As[kc+3][row]=av.w;
    int bk = tid >> 4, c0 = (tid & 15) << 2;
    *(float4*)&Bs[bk][c0] = *(const float4*)(Ai + (size_t)(kt+bk)*N + bn*64 + c0);
    __syncthreads();
#pragma unroll
    for (int kk = 0; kk < 16; ++kk){
      float4 a = *(const float4*)&As[kk][ty*4];
      float4 b = *(const float4*)&Bs[kk][tx*4];
      float aa[4]={a.x,a.y,a.z,a.w}, bb[4]={b.x,b.y,b.z,b.w};
#pragma unroll
      for (int ii=0; ii<4; ++ii)
#pragma unroll
        for (int jj=0; jj<4; ++jj) acc[ii][jj] += aa[ii]*bb[jj];
    }
    __syncthreads();
  }
#pragma unroll
  for (int ii=0; ii<4; ++ii){
    float4 vst = make_float4(acc[ii][0],acc[ii][1],acc[ii][2],acc[ii][3]);
    *(float4*)(C + (size_t)(bm*64+ty*4+ii)*N + bn*64 + tx*4) = vst;
  }
}

// ---- g[k] = GA^k GB ----
__global__ void k_g(const float* __restrict__ QT, const float* __restrict__ GB,
                    float* __restrict__ g){
  int kb = blockIdx.x;
  int n = threadIdx.x;
  if (kb == 0){ g[n] = GB[n]; return; }
  const float* Qk = QT + (size_t)kb*(N*N);
  float acc = 0.0f;
  for (int m = 0; m < N; ++m) acc += Qk[m*N + n]*GB[m];
  g[kb*N + n] = acc;
}

// ---- within-chunk causal conv ----
__global__ __launch_bounds__(256) void k_fill_local(const float* __restrict__ fq,
                             const float* __restrict__ fk, const float* __restrict__ fv,
                             const float* __restrict__ g, float* __restrict__ cs){
  int tile = blockIdx.x;
  int s = blockIdx.y, j = blockIdx.z;
  const float* f = (s==0)? fq : (s==1)? fk : fv;
  __shared__ float flp[256];
  __shared__ __align__(16) float Bs[16][68];
  int tx = threadIdx.x, ty = threadIdx.y;
  int tid = ty*16 + tx;
  flp[tid] = (tid < 128) ? 0.0f : f[j*L + tid - 128];
  int ti = tile >> 1, tj = tile & 1;
  float acc[4][4] = {};
  int kmax = (ti == 0) ? 64 : 128;
  for (int kt = 0; kt < kmax; kt += 16){
    int bk = tid >> 4, c0 = (tid & 15) << 2;
    *(float4*)&Bs[bk][c0] = *(const float4*)(g + (size_t)(kt+bk)*N + tj*64 + c0);
    __syncthreads();
#pragma unroll
    for (int kk = 0; kk < 16; ++kk){
      float4 b = *(const float4*)&Bs[kk][tx*4];
      int base = 128 + ti*64 + ty*4 - kt - kk;
      float aa[4] = {flp[base], flp[base+1], flp[base+2], flp[base+3]};
      float bb[4] = {b.x, b.y, b.z, b.w};
#pragma unroll
      for (int ii=0; ii<4; ++ii)
#pragma unroll
        for (int jj=0; jj<4; ++jj) acc[ii][jj] += aa[ii]*bb[jj];
    }
    __syncthreads();
  }
#pragma unroll
  for (int ii=0; ii<4; ++ii){
    int row = ti*64 + ty*4 + ii;
    float4 vst = make_float4(acc[ii][0],acc[ii][1],acc[ii][2],acc[ii][3]);
    *(float4*)(cs + ((size_t)s*S + (size_t)j*L + row)*N + tj*64 + tx*4) = vst;
  }
}

// ---- sequential chunk-boundary scan ----
__global__ void k_bscan(const float* __restrict__ QT, const float* __restrict__ cs,
                        float* __restrict__ bounds){
  __shared__ float bc[3][N];
  __shared__ float bnx[3][N];
  int tid = threadIdx.x;
  int s = tid >> 7, n = tid & 127;
  const float* QL = QT + (size_t)L*(N*N);
  bc[s][n] = 0.0f;
  bounds[(0*3+s)*N + n] = 0.0f;
  __syncthreads();
  for (int j = 0; j < NC; ++j){
    float acc = cs[((size_t)s*S + (size_t)j*L + 127)*N + n];
    for (int m = 0; m < N; ++m) acc += QL[m*N+n]*bc[s][m];
    bnx[s][n] = acc;
    bounds[((j+1)*3+s)*N + n] = acc;
    __syncthreads();
    bc[s][n] = bnx[s][n];
    __syncthreads();
  }
}

// ---- boundary fill: cs[s][jL+i] += GA^{i+1} b_j  (4-task register blocking) ----
__global__ __launch_bounds__(256) void k_fill_bound(const float* __restrict__ QT,
                          const float* __restrict__ bounds, float* __restrict__ cs){
  int i = blockIdx.x;
  int jg = blockIdx.y;
  __shared__ float Qs[N*N];
  int tid = threadIdx.x;
  int p = tid >> 7, n = tid & 127;
  const float* Qg = QT + (size_t)(i+1)*(N*N);
  for (int idx = tid; idx < N*N; idx += 256) Qs[idx] = Qg[idx];
  __syncthreads();
  for (int r4 = 0; r4 < 24; r4 += 4){
    int task0 = jg*48 + p*24 + r4;
    const float* b0 = bounds + (size_t)task0*N;
    const float* b1 = b0 + N;
    const float* b2 = b0 + 2*N;
    const float* b3 = b0 + 3*N;
    float a0=0.f, a1=0.f, a2=0.f, a3=0.f;
#pragma unroll 4
    for (int m = 0; m < N; ++m){
      float q = Qs[m*N + n];
      a0 += q*b0[m]; a1 += q*b1[m]; a2 += q*b2[m]; a3 += q*b3[m];
    }
    float av[4] = {a0, a1, a2, a3};
#pragma unroll
    for (int q4 = 0; q4 < 4; ++q4){
      int task = task0 + q4;
      int j = task/3, s2 = task - 3*j;
      cs[((size_t)s2*S + (size_t)j*L + i)*N + n] += av[q4];
    }
  }
}

// ---- split q,k states into bf16 hi/lo (natural [2*S][N] layout) ----
__global__ void k_split_qk(const float* __restrict__ cs,
                           u16* __restrict__ sh, u16* __restrict__ sl){
  size_t i = ((size_t)blockIdx.x*256 + threadIdx.x) << 2;
  float4 v = *(const float4*)(cs + i);
  us4 h, l;
  h[0]=f2bf(v.x); l[0]=f2bf(v.x - bf2f(h[0]));
  h[1]=f2bf(v.y); l[1]=f2bf(v.y - bf2f(h[1]));
  h[2]=f2bf(v.z); l[2]=f2bf(v.z - bf2f(h[2]));
  h[3]=f2bf(v.w); l[3]=f2bf(v.w - bf2f(h[3]));
  *(us4*)(sh + i) = h;
  *(us4*)(sl + i) = l;
}

// ---- split v states into bf16 hi/lo, k-tiled transpose: [S/32][128][32] ----
__global__ __launch_bounds__(256) void k_split_vT(const float* __restrict__ vs,
                           u16* __restrict__ vth, u16* __restrict__ vtl){
  __shared__ u16 Th[128*72];
  __shared__ u16 Tl[128*72];
  int t0 = blockIdx.x * 64;
  int tid = threadIdx.x;
  for (int c = tid; c < 2048; c += 256){
    int i = c >> 5, n0 = (c & 31) << 2;
    float4 v = *(const float4*)(vs + (size_t)(t0 + i)*N + n0);
    u16 h;
    h = f2bf(v.x); Th[(n0+0)*72 + i] = h; Tl[(n0+0)*72 + i] = f2bf(v.x - bf2f(h));
    h = f2bf(v.y); Th[(n0+1)*72 + i] = h; Tl[(n0+1)*72 + i] = f2bf(v.y - bf2f(h));
    h = f2bf(v.z); Th[(n0+2)*72 + i] = h; Tl[(n0+2)*72 + i] = f2bf(v.z - bf2f(h));
    h = f2bf(v.w); Th[(n0+3)*72 + i] = h; Tl[(n0+3)*72 + i] = f2bf(v.w - bf2f(h));
  }
  __syncthreads();
  for (int c = tid; c < 1024; c += 256){
    int n = c >> 3, tc = (c & 7) << 3;
    int tile = (t0 + tc) >> 5;
    int kin  = (t0 + tc) & 31;
    size_t dst = (size_t)tile*4096 + n*32 + kin;
    *(us8*)(vth + dst) = *(const us8*)&Th[n*72 + tc];
    *(us8*)(vtl + dst) = *(const us8*)&Tl[n*72 + tc];
  }
}

// ---- stats-only QK^T (swapped: S^T = K @ Q^T), per-(col-block,row) max/sumexp ----
__global__ __launch_bounds__(256) void k_stats(
    const u16* __restrict__ qh, const u16* __restrict__ ql,
    const u16* __restrict__ kh, const u16* __restrict__ kl,
    float* __restrict__ pmax, float* __restrict__ psum){
  __shared__ __align__(16) u16 Ah[128*40], Al[128*40], Bh[128*40], Bl[128*40];
  __shared__ float wst[2][128][2];
  int bm = blockIdx.y, bn = blockIdx.x;
  int tid = threadIdx.x;
  int lane = tid & 63, w = tid >> 6;
  int l15 = lane & 15, l4 = lane >> 4;
  int wr = w >> 1, wc = w & 1;          // wr: seq-half, wc: q-half
  int kg = l4 << 3;
  f32x4 accs[4][4] = {};                // [si(seq)][qi(q)]
  for (int kt = 0; kt < N; kt += 32){
    for (int c = tid; c < 512; c += 256){
      int r = c >> 2, k8 = (c & 3) << 3;
      size_t ga = (size_t)(bm*128 + r)*N + kt + k8;   // q rows
      size_t gb = (size_t)(bn*128 + r)*N + kt + k8;   // k rows (seq)
      int lo = r*40 + k8;
      *(us8*)&Ah[lo] = *(const us8*)(qh + ga);
      *(us8*)&Al[lo] = *(const us8*)(ql + ga);
      *(us8*)&Bh[lo] = *(const us8*)(kh + gb);
      *(us8*)&Bl[lo] = *(const us8*)(kl + gb);
    }
    __syncthreads();
    bf16x8 kfh[4], kfl[4], qfh[4], qfl[4];
#pragma unroll
    for (int si = 0; si < 4; ++si){
      kfh[si] = *(const bf16x8*)&Bh[(wr*64 + si*16 + l15)*40 + kg];
      kfl[si] = *(const bf16x8*)&Bl[(wr*64 + si*16 + l15)*40 + kg];
    }
#pragma unroll
    for (int qi = 0; qi < 4; ++qi){
      qfh[qi] = *(const bf16x8*)&Ah[(wc*64 + qi*16 + l15)*40 + kg];
      qfl[qi] = *(const bf16x8*)&Al[(wc*64 + qi*16 + l15)*40 + kg];
    }
#pragma unroll
    for (int si = 0; si < 4; ++si)
#pragma unroll
      for (int qi = 0; qi < 4; ++qi){
        accs[si][qi] = __builtin_amdgcn_mfma_f32_16x16x32_bf16(kfh[si], qfh[qi], accs[si][qi], 0,0,0);
        accs[si][qi] = __builtin_amdgcn_mfma_f32_16x16x32_bf16(kfh[si], qfl[qi], accs[si][qi], 0,0,0);
        accs[si][qi] = __builtin_amdgcn_mfma_f32_16x16x32_bf16(kfl[si], qfh[qi], accs[si][qi], 0,0,0);
      }
    __syncthreads();
  }
  float mq[4], sq[4];
#pragma unroll
  for (int qi = 0; qi < 4; ++qi){
    float m = -3.0e38f;
#pragma unroll
    for (int si = 0; si < 4; ++si)
#pragma unroll
      for (int r = 0; r < 4; ++r) m = fmaxf(m, accs[si][qi][r]);
    mq[qi] = m * SCL;
  }
#pragma unroll
  for (int qi = 0; qi < 4; ++qi){
    mq[qi] = fmaxf(mq[qi], __shfl_xor(mq[qi], 16, 64));
    mq[qi] = fmaxf(mq[qi], __shfl_xor(mq[qi], 32, 64));
  }
#pragma unroll
  for (int qi = 0; qi < 4; ++qi){
    float s = 0.0f;
#pragma unroll
    for (int si = 0; si < 4; ++si)
#pragma unroll
      for (int r = 0; r < 4; ++r) s += __expf(accs[si][qi][r]*SCL - mq[qi]);
    sq[qi] = s;
  }
#pragma unroll
  for (int qi = 0; qi < 4; ++qi){
    sq[qi] += __shfl_xor(sq[qi], 16, 64);
    sq[qi] += __shfl_xor(sq[qi], 32, 64);
  }
  if (l4 == 0){
#pragma unroll
    for (int qi = 0; qi < 4; ++qi){
      int ql_ = wc*64 + qi*16 + l15;
      wst[wr][ql_][0] = mq[qi];
      wst[wr][ql_][1] = sq[qi];
    }
  }
  __syncthreads();
  if (tid < 128){
    float m0 = wst[0][tid][0], m1 = wst[1][tid][0];
    float m = fmaxf(m0, m1);
    float Z = wst[0][tid][1]*__expf(m0 - m) + wst[1][tid][1]*__expf(m1 - m);
    pmax[(size_t)bn*S + bm*128 + tid] = m;
    psum[(size_t)bn*S + bm*128 + tid] = Z;
  }
}

// ---- merge per-col-block partials -> per-row (max, 1/Z) ----
__global__ void k_rowstat(const float* __restrict__ pmax, const float* __restrict__ psum,
                          float* __restrict__ rowm, float* __restrict__ rowinv){
  int t = blockIdx.x*256 + threadIdx.x;
  float m = -3.0e38f;
  for (int b = 0; b < 64; ++b) m = fmaxf(m, pmax[(size_t)b*S + t]);
  float Z = 0.0f;
  for (int b = 0; b < 64; ++b) Z += psum[(size_t)b*S + t]*__expf(pmax[(size_t)b*S + t] - m);
  rowm[t] = m;
  rowinv[t] = 1.0f/Z;
}

// ---- fused: recompute S^T, normalize, write attn, FULL-RATE PV ----
// Wave owns 32 q (2x16). S^T = mfma(K,Q) as k_stats. In-register exchange
// (32 shfl) converts the swapped-S layout into PV A-fragments with 8 seq/lane,
// so PV runs full K=32 MFMAs. K in LDS (XOR-swizzled), V in LDS (pad 40),
// Q re-read from global (L2-hot) each ko.
__global__ __launch_bounds__(256) void k_ctx(
    float* __restrict__ attn,
    const float* __restrict__ rowm, const float* __restrict__ rowinv,
    const u16* __restrict__ qh, const u16* __restrict__ ql,
    const u16* __restrict__ kh, const u16* __restrict__ kl,
    const u16* __restrict__ vth, const u16* __restrict__ vtl,  // [S/32][128][32]
    float* __restrict__ dst, int mode){
  __shared__ __align__(16) u16 Ksh[32*128], Ksl[32*128];   // XOR-swizzled, 16 KB
  __shared__ __align__(16) u16 Vsh[128*40], Vsl[128*40];   // pad 40, 20 KB
  int bm = blockIdx.x, kz = blockIdx.y;
  int tid = threadIdx.x, lane = tid & 63, w = tid >> 6;
  int l15 = lane & 15, l4 = lane >> 4;
  int kg = l4 << 3;
  const int KC = S / KSPLIT;   // 512
  int k0 = kz*KC;
  int qbase = bm*128 + w*32;
  float rm[2], ri[2];
  rm[0] = rowm[qbase + l15];        ri[0] = rowinv[qbase + l15];
  rm[1] = rowm[qbase + 16 + l15];   ri[1] = rowinv[qbase + 16 + l15];
  // shfl source lanes for the exchange (g = j>>2)
  int src0 = l15 + 32*(l4 & 1);     // g = 0
  int src1 = src0 + 16;             // g = 1
  bool hi_si = (l4 >> 1);
  f32x4 acco[2][8] = {};   // [qi][ni]
  for (int ko = 0; ko < KC; ko += 32){
    int cb = k0 + ko;
    // ---- stage K (XOR-swizzled) and V (pad 40) ----
    for (int c = tid; c < 512; c += 256){
      int rr = c >> 4, c8 = (c & 15) << 3;
      int lo = (rr*128 + c8) ^ ((rr & 7) << 3);
      size_t gk = (size_t)(cb + rr)*N + c8;
      *(us8*)&Ksh[lo] = *(const us8*)(kh + gk);
      *(us8*)&Ksl[lo] = *(const us8*)(kl + gk);
    }
    {
      const u16* sh = vth + (size_t)(cb >> 5)*4096;
      const u16* sl = vtl + (size_t)(cb >> 5)*4096;
      for (int c = tid; c < 512; c += 256){
        int lo = (c >> 2)*40 + ((c & 3) << 3);
        *(us8*)&Vsh[lo] = *(const us8*)(sh + (size_t)c*8);
        *(us8*)&Vsl[lo] = *(const us8*)(sl + (size_t)c*8);
      }
    }
    __syncthreads();
    // ---- S^T: accs[si][qi], K from LDS, Q from global (L2) ----
    f32x4 accs[2][2] = {};
#pragma unroll
    for (int kt = 0; kt < 4; ++kt){
      bf16x8 qfh[2], qfl[2], kfh[2], kfl[2];
#pragma unroll
      for (int qi = 0; qi < 2; ++qi){
        size_t gq = (size_t)(qbase + qi*16 + l15)*N + kt*32 + kg;
        qfh[qi] = *(const bf16x8*)(qh + gq);
        qfl[qi] = *(const bf16x8*)(ql + gq);
      }
#pragma unroll
      for (int si = 0; si < 2; ++si){
        int lo = (((si*16 + l15)*128 + kt*32 + kg) ^ (((si*16 + l15) & 7) << 3));
        kfh[si] = *(const bf16x8*)&Ksh[lo];
        kfl[si] = *(const bf16x8*)&Ksl[lo];
      }
#pragma unroll
      for (int si = 0; si < 2; ++si)
#pragma unroll
        for (int qi = 0; qi < 2; ++qi){
          accs[si][qi] = __builtin_amdgcn_mfma_f32_16x16x32_bf16(kfh[si], qfh[qi], accs[si][qi], 0,0,0);
          accs[si][qi] = __builtin_amdgcn_mfma_f32_16x16x32_bf16(kfh[si], qfl[qi], accs[si][qi], 0,0,0);
          accs[si][qi] = __builtin_amdgcn_mfma_f32_16x16x32_bf16(kfl[si], qfh[qi], accs[si][qi], 0,0,0);
        }
    }
    // ---- exchange -> y[qi][j] = raw S at (q=16qi+l15, seq=8*l4+j) ----
    bf16x8 pah[2], pal[2];
#pragma unroll
    for (int qi = 0; qi < 2; ++qi){
      float y[8];
#pragma unroll
      for (int r = 0; r < 4; ++r){
        float t0 = __shfl(accs[0][qi][r], src0, 64);
        float t1 = __shfl(accs[1][qi][r], src0, 64);
        y[r] = hi_si ? t1 : t0;
        float u0 = __shfl(accs[0][qi][r], src1, 64);
        float u1 = __shfl(accs[1][qi][r], src1, 64);
        y[4+r] = hi_si ? u1 : u0;
      }
      // normalize + attn store (two float4) + bf16 hi/lo A-fragments
      float p[8];
#pragma unroll
      for (int j = 0; j < 8; ++j) p[j] = __expf(y[j]*SCL - rm[qi]) * ri[qi];
      int q = qbase + qi*16 + l15;
      *(float4*)(attn + (size_t)q*S + cb + kg)     = make_float4(p[0],p[1],p[2],p[3]);
      *(float4*)(attn + (size_t)q*S + cb + kg + 4) = make_float4(p[4],p[5],p[6],p[7]);
      bf16x8 ah, al;
#pragma unroll
      for (int j = 0; j < 8; ++j){
        u16 h = f2bf(p[j]);
        ah[j] = (short)h;
        al[j] = (short)f2bf(p[j] - bf2f(h));
      }
      pah[qi] = ah; pal[qi] = al;
    }
    // ---- PV full-rate: acco[qi][ni] += P(32seq) x V ----
#pragma unroll
    for (int ni = 0; ni < 8; ++ni){
      int lo = (ni*16 + l15)*40 + kg;
      bf16x8 vbh = *(const bf16x8*)&Vsh[lo];
      bf16x8 vbl = *(const bf16x8*)&Vsl[lo];
#pragma unroll
      for (int qi = 0; qi < 2; ++qi){
        acco[qi][ni] = __builtin_amdgcn_mfma_f32_16x16x32_bf16(pah[qi], vbh, acco[qi][ni], 0,0,0);
        acco[qi][ni] = __builtin_amdgcn_mfma_f32_16x16x32_bf16(pah[qi], vbl, acco[qi][ni], 0,0,0);
        acco[qi][ni] = __builtin_amdgcn_mfma_f32_16x16x32_bf16(pal[qi], vbh, acco[qi][ni], 0,0,0);
      }
    }
    __syncthreads();   // before next iter's staging overwrites K/V
  }
  // epilogue: row q = qbase + 16qi + 4*l4 + r, col n = ni*16 + l15
  if (mode == 0){
    float* P = dst + (size_t)kz*S*N;
#pragma unroll
    for (int qi = 0; qi < 2; ++qi)
#pragma unroll
      for (int ni = 0; ni < 8; ++ni)
#pragma unroll
        for (int r = 0; r < 4; ++r){
          int q = qbase + qi*16 + (l4<<2) + r;
          P[(size_t)q*N + ni*16 + l15] = acco[qi][ni][r];
        }
  } else {
#pragma unroll
    for (int qi = 0; qi < 2; ++qi)
#pragma unroll
      for (int ni = 0; ni < 8; ++ni)
#pragma unroll
        for (int r = 0; r < 4; ++r){
          int q = qbase + qi*16 + (l4<<2) + r;
          atomicAdd(&dst[(size_t)q*N + ni*16 + l15], acco[qi][ni][r]);
        }
  }
}

// ---- reduce partials -> ctx ----
__global__ __launch_bounds__(256) void k_reduce(const float* __restrict__ part,
                                                float* __restrict__ ctx){
  size_t idx = (size_t)blockIdx.x*256 + threadIdx.x;
  const float4* p4 = (const float4*)part;
  float4 acc = p4[idx];
  const size_t stride = (size_t)S*N/4;
#pragma unroll
  for (int kz = 1; kz < KSPLIT; ++kz){
    float4 v = p4[(size_t)kz*stride + idx];
    acc.x += v.x; acc.y += v.y; acc.z += v.z; acc.w += v.w;
  }
  ((float4*)ctx)[idx] = acc;
}

// ---- out = ctx @ Wp + bp ----
__global__ __launch_bounds__(256) void k_out(const float* __restrict__ ctx,
                   const float* __restrict__ Wp, const float* __restrict__ bp,
                   float* __restrict__ out){
  __shared__ __align__(16) float As[16][68];
  __shared__ __align__(16) float Bs[16][68];
  int bn = blockIdx.x;
  int bm = blockIdx.y;
  int tx = threadIdx.x, ty = threadIdx.y;
  int tid = ty*16 + tx;
  float acc[4][4] = {};
  for (int kt = 0; kt < N; kt += 16){
    int row = tid >> 2, kc = (tid & 3) << 2;
    float4 av = *(const float4*)(ctx + (size_t)(bm*64+row)*N + kt + kc);
    As[kc+0][row]=av.x; As[kc+1][row]=av.y; As[kc+2][row]=av.z; As[kc+3][row]=av.w;
    int bk = tid >> 4, c0 = (tid & 15) << 2;
#pragma unroll
    for (int jj = 0; jj < 4; ++jj){
      int c = bn*64 + c0 + jj;
      Bs[bk][c0+jj] = (c < OD) ? Wp[(size_t)(kt+bk)*OD + c] : 0.0f;
    }
    __syncthreads();
#pragma unroll
    for (int kk = 0; kk < 16; ++kk){
      float4 a = *(const float4*)&As[kk][ty*4];
      float4 b = *(const float4*)&Bs[kk][tx*4];
      float aa[4]={a.x,a.y,a.z,a.w}, bb[4]={b.x,b.y,b.z,b.w};
#pragma unroll
      for (int ii=0; ii<4; ++ii)
#pragma unroll
        for (int jj=0; jj<4; ++jj) acc[ii][jj] += aa[ii]*bb[jj];
    }
    __syncthreads();
  }
#pragma unroll
  for (int ii=0; ii<4; ++ii){
    int r = bm*64 + ty*4 + ii;
#pragma unroll
    for (int jj=0; jj<4; ++jj){
      int c = bn*64 + tx*4 + jj;
      if (c < OD) out[(size_t)r*OD + c] = acc[ii][jj] + bp[c];
    }
  }
}

extern "C" void kernel_launch(void* const* d_in, const int* in_sizes, int n_in,
                              void* d_out, int out_size, void* d_ws, size_t ws_size,
                              hipStream_t stream){
  const float* fq = (const float*)d_in[0];
  const float* fk = (const float*)d_in[1];
  const float* fv = (const float*)d_in[2];
  const float* GA = (const float*)d_in[3];
  const float* GB = (const float*)d_in[4];
  const float* Wp = (const float*)d_in[5];
  const float* bp = (const float*)d_in[6];
  float* out  = (float*)d_out;
  float* attn = out + (size_t)S*OD;

  float* ws     = (float*)d_ws;
  float* QT     = ws;                                // 129*16384
  float* g      = QT + (size_t)129*N*N;              // 128*128
  float* bounds = g + (size_t)L*N;                   // 65*3*128
  float* cs     = bounds + (size_t)(NC+1)*3*N;       // 3*8192*128
  float* ctx    = cs + (size_t)3*S*N;                // 8192*128
  u16*   qkh    = (u16*)(ctx + (size_t)S*N);         // 2*S*N u16
  u16*   qkl    = qkh + (size_t)2*S*N;               // 2*S*N u16
  u16*   vth    = qkl + (size_t)2*S*N;               // S*N u16 tiled [S/32][128][32]
  u16*   vtl    = vth + (size_t)S*N;                 // S*N u16
  float* pmax   = (float*)(vtl + (size_t)S*N);       // 64*8192
  float* psum   = pmax + (size_t)(S/128)*S;          // 64*8192
  float* rowm   = psum + (size_t)(S/128)*S;          // 8192
  float* rowinv = rowm + S;                          // 8192
  float* part   = rowinv + S;                        // KSPLIT*8192*128 (optional)
  size_t need_part = ((size_t)(part - ws) + (size_t)KSPLIT*S*N) * sizeof(float);
  bool use_part = (ws_size >= need_part);

  k_copyT<<<64, 256, 0, stream>>>(GA, QT + (size_t)N*N);
  for (int m = 1; m < L; m <<= 1)
    k_powmm<<<dim3(2,2,m), dim3(16,16), 0, stream>>>(QT, m);
  k_g<<<128, 128, 0, stream>>>(QT, GB, g);
  k_fill_local<<<dim3(4,3,NC), dim3(16,16), 0, stream>>>(fq, fk, fv, g, cs);
  k_bscan<<<1, 384, 0, stream>>>(QT, cs, bounds);
  k_fill_bound<<<dim3(L,4), 256, 0, stream>>>(QT, bounds, cs);

  k_split_qk<<<(2*S*N)/1024, 256, 0, stream>>>(cs, qkh, qkl);
  k_split_vT<<<S/64, 256, 0, stream>>>(cs + (size_t)2*S*N, vth, vtl);

  k_stats<<<dim3(S/128, S/128), 256, 0, stream>>>(
      qkh, qkl, qkh + (size_t)S*N, qkl + (size_t)S*N, pmax, psum);
  k_rowstat<<<S/256, 256, 0, stream>>>(pmax, psum, rowm, rowinv);
  if (use_part){
    k_ctx<<<dim3(S/128, KSPLIT), 256, 0, stream>>>(attn, rowm, rowinv,
        qkh, qkl, qkh + (size_t)S*N, qkl + (size_t)S*N, vth, vtl, part, 0);
    k_reduce<<<(S*N/4)/256, 256, 0, stream>>>(part, ctx);
  } else {
    hipMemsetAsync(ctx, 0, (size_t)S*N*sizeof(float), stream);
    k_ctx<<<dim3(S/128, KSPLIT), 256, 0, stream>>>(attn, rowm, rowinv,
        qkh, qkl, qkh + (size_t)S*N, qkl + (size_t)S*N, vth, vtl, ctx, 1);
  }
  k_out<<<dim3(16, S/64), dim3(16,16), 0, stream>>>(ctx, Wp, bp, out);
}

// Round 7
// 833.970 us; speedup vs baseline: 1.1761x; 1.0740x over previous
//
#include <hip/hip_runtime.h>

static constexpr int N  = 128;   // N_STATE
static constexpr int S  = 8192;  // SEQ
static constexpr int L  = 128;   // chunk length
static constexpr int NC = 64;    // S/L
static constexpr int OD = 1000;  // OUT_DIM
static constexpr int KSPLIT = 16;
#define SCL 0.25f                // 1/sqrt(D_HEAD=16), exact power of 2

typedef unsigned short u16;
typedef __attribute__((ext_vector_type(4))) unsigned short us4;
typedef __attribute__((ext_vector_type(8))) unsigned short us8;
typedef __attribute__((ext_vector_type(8))) short bf16x8;   // 8 bf16 = 4 VGPRs
typedef __attribute__((ext_vector_type(4))) float f32x4;

__device__ __forceinline__ u16 f2bf(float x){
  unsigned u = __float_as_uint(x);
  u += 0x7FFFu + ((u >> 16) & 1u);   // RNE to bf16
  return (u16)(u >> 16);
}
__device__ __forceinline__ float bf2f(u16 h){
  return __uint_as_float(((unsigned)h) << 16);
}

// ---- QT[1] = GA^T ----
__global__ void k_copyT(const float* __restrict__ GA, float* __restrict__ QT1){
  int idx = blockIdx.x*256 + threadIdx.x;
  int m = idx >> 7, n = idx & 127;
  QT1[idx] = GA[n*N + m];
}

// ---- QT[mlev+i] = QT[mlev] @ QT[i] ----
__global__ __launch_bounds__(256) void k_powmm(float* QT, int mlev){
  int i = blockIdx.z + 1;
  const float* Am = QT + (size_t)mlev*(N*N);
  const float* Ai = QT + (size_t)i*(N*N);
  float* C = QT + (size_t)(mlev+i)*(N*N);
  __shared__ __align__(16) float As[16][68];
  __shared__ __align__(16) float Bs[16][68];
  int bm = blockIdx.y, bn = blockIdx.x;
  int tx = threadIdx.x, ty = threadIdx.y;
  int tid = ty*16 + tx;
  float acc[4][4] = {};
  for (int kt = 0; kt < N; kt += 16){
    int row = tid >> 2, kc = (tid & 3) << 2;
    float4 av = *(const float4*)(Am + (size_t)(bm*64+row)*N + kt + kc);
    As[kc+0][row]=av.x; As[kc+1][row]=av.y; As[kc+2][row]=av.z; As[kc+3][row]=av.w;
    int bk = tid >> 4, c0 = (tid & 15) << 2;
    *(float4*)&Bs[bk][c0] = *(const float4*)(Ai + (size_t)(kt+bk)*N + bn*64 + c0);
    __syncthreads();
#pragma unroll
    for (int kk = 0; kk < 16; ++kk){
      float4 a = *(const float4*)&As[kk][ty*4];
      float4 b = *(const float4*)&Bs[kk][tx*4];
      float aa[4]={a.x,a.y,a.z,a.w}, bb[4]={b.x,b.y,b.z,b.w};
#pragma unroll
      for (int ii=0; ii<4; ++ii)
#pragma unroll
        for (int jj=0; jj<4; ++jj) acc[ii][jj] += aa[ii]*bb[jj];
    }
    __syncthreads();
  }
#pragma unroll
  for (int ii=0; ii<4; ++ii){
    float4 vst = make_float4(acc[ii][0],acc[ii][1],acc[ii][2],acc[ii][3]);
    *(float4*)(C + (size_t)(bm*64+ty*4+ii)*N + bn*64 + tx*4) = vst;
  }
}

// ---- g[k] = GA^k GB ----
__global__ void k_g(const float* __restrict__ QT, const float* __restrict__ GB,
                    float* __restrict__ g){
  int kb = blockIdx.x;
  int n = threadIdx.x;
  if (kb == 0){ g[n] = GB[n]; return; }
  const float* Qk = QT + (size_t)kb*(N*N);
  float acc = 0.0f;
  for (int m = 0; m < N; ++m) acc += Qk[m*N + n]*GB[m];
  g[kb*N + n] = acc;
}

// ---- within-chunk causal conv ----
__global__ __launch_bounds__(256) void k_fill_local(const float* __restrict__ fq,
                             const float* __restrict__ fk, const float* __restrict__ fv,
                             const float* __restrict__ g, float* __restrict__ cs){
  int tile = blockIdx.x;
  int s = blockIdx.y, j = blockIdx.z;
  const float* f = (s==0)? fq : (s==1)? fk : fv;
  __shared__ float flp[256];
  __shared__ __align__(16) float Bs[16][68];
  int tx = threadIdx.x, ty = threadIdx.y;
  int tid = ty*16 + tx;
  flp[tid] = (tid < 128) ? 0.0f : f[j*L + tid - 128];
  int ti = tile >> 1, tj = tile & 1;
  float acc[4][4] = {};
  int kmax = (ti == 0) ? 64 : 128;
  for (int kt = 0; kt < kmax; kt += 16){
    int bk = tid >> 4, c0 = (tid & 15) << 2;
    *(float4*)&Bs[bk][c0] = *(const float4*)(g + (size_t)(kt+bk)*N + tj*64 + c0);
    __syncthreads();
#pragma unroll
    for (int kk = 0; kk < 16; ++kk){
      float4 b = *(const float4*)&Bs[kk][tx*4];
      int base = 128 + ti*64 + ty*4 - kt - kk;
      float aa[4] = {flp[base], flp[base+1], flp[base+2], flp[base+3]};
      float bb[4] = {b.x, b.y, b.z, b.w};
#pragma unroll
      for (int ii=0; ii<4; ++ii)
#pragma unroll
        for (int jj=0; jj<4; ++jj) acc[ii][jj] += aa[ii]*bb[jj];
    }
    __syncthreads();
  }
#pragma unroll
  for (int ii=0; ii<4; ++ii){
    int row = ti*64 + ty*4 + ii;
    float4 vst = make_float4(acc[ii][0],acc[ii][1],acc[ii][2],acc[ii][3]);
    *(float4*)(cs + ((size_t)s*S + (size_t)j*L + row)*N + tj*64 + tx*4) = vst;
  }
}

// ---- sequential chunk-boundary scan ----
__global__ void k_bscan(const float* __restrict__ QT, const float* __restrict__ cs,
                        float* __restrict__ bounds){
  __shared__ float bc[3][N];
  __shared__ float bnx[3][N];
  int tid = threadIdx.x;
  int s = tid >> 7, n = tid & 127;
  const float* QL = QT + (size_t)L*(N*N);
  bc[s][n] = 0.0f;
  bounds[(0*3+s)*N + n] = 0.0f;
  __syncthreads();
  for (int j = 0; j < NC; ++j){
    float acc = cs[((size_t)s*S + (size_t)j*L + 127)*N + n];
    for (int m = 0; m < N; ++m) acc += QL[m*N+n]*bc[s][m];
    bnx[s][n] = acc;
    bounds[((j+1)*3+s)*N + n] = acc;
    __syncthreads();
    bc[s][n] = bnx[s][n];
    __syncthreads();
  }
}

// ---- boundary fill: cs[s][jL+i] += GA^{i+1} b_j  (4-task register blocking) ----
__global__ __launch_bounds__(256) void k_fill_bound(const float* __restrict__ QT,
                          const float* __restrict__ bounds, float* __restrict__ cs){
  int i = blockIdx.x;
  int jg = blockIdx.y;
  __shared__ float Qs[N*N];
  int tid = threadIdx.x;
  int p = tid >> 7, n = tid & 127;
  const float* Qg = QT + (size_t)(i+1)*(N*N);
  for (int idx = tid; idx < N*N; idx += 256) Qs[idx] = Qg[idx];
  __syncthreads();
  for (int r4 = 0; r4 < 24; r4 += 4){
    int task0 = jg*48 + p*24 + r4;
    const float* b0 = bounds + (size_t)task0*N;
    const float* b1 = b0 + N;
    const float* b2 = b0 + 2*N;
    const float* b3 = b0 + 3*N;
    float a0=0.f, a1=0.f, a2=0.f, a3=0.f;
#pragma unroll 4
    for (int m = 0; m < N; ++m){
      float q = Qs[m*N + n];
      a0 += q*b0[m]; a1 += q*b1[m]; a2 += q*b2[m]; a3 += q*b3[m];
    }
    float av[4] = {a0, a1, a2, a3};
#pragma unroll
    for (int q4 = 0; q4 < 4; ++q4){
      int task = task0 + q4;
      int j = task/3, s2 = task - 3*j;
      cs[((size_t)s2*S + (size_t)j*L + i)*N + n] += av[q4];
    }
  }
}

// ---- split q,k states into bf16 hi/lo (natural [2*S][N] layout) ----
__global__ void k_split_qk(const float* __restrict__ cs,
                           u16* __restrict__ sh, u16* __restrict__ sl){
  size_t i = ((size_t)blockIdx.x*256 + threadIdx.x) << 2;
  float4 v = *(const float4*)(cs + i);
  us4 h, l;
  h[0]=f2bf(v.x); l[0]=f2bf(v.x - bf2f(h[0]));
  h[1]=f2bf(v.y); l[1]=f2bf(v.y - bf2f(h[1]));
  h[2]=f2bf(v.z); l[2]=f2bf(v.z - bf2f(h[2]));
  h[3]=f2bf(v.w); l[3]=f2bf(v.w - bf2f(h[3]));
  *(us4*)(sh + i) = h;
  *(us4*)(sl + i) = l;
}

// ---- split v states into bf16 hi/lo, k-tiled transpose: [S/32][128][32] ----
__global__ __launch_bounds__(256) void k_split_vT(const float* __restrict__ vs,
                           u16* __restrict__ vth, u16* __restrict__ vtl){
  __shared__ u16 Th[128*72];
  __shared__ u16 Tl[128*72];
  int t0 = blockIdx.x * 64;
  int tid = threadIdx.x;
  for (int c = tid; c < 2048; c += 256){
    int i = c >> 5, n0 = (c & 31) << 2;
    float4 v = *(const float4*)(vs + (size_t)(t0 + i)*N + n0);
    u16 h;
    h = f2bf(v.x); Th[(n0+0)*72 + i] = h; Tl[(n0+0)*72 + i] = f2bf(v.x - bf2f(h));
    h = f2bf(v.y); Th[(n0+1)*72 + i] = h; Tl[(n0+1)*72 + i] = f2bf(v.y - bf2f(h));
    h = f2bf(v.z); Th[(n0+2)*72 + i] = h; Tl[(n0+2)*72 + i] = f2bf(v.z - bf2f(h));
    h = f2bf(v.w); Th[(n0+3)*72 + i] = h; Tl[(n0+3)*72 + i] = f2bf(v.w - bf2f(h));
  }
  __syncthreads();
  for (int c = tid; c < 1024; c += 256){
    int n = c >> 3, tc = (c & 7) << 3;
    int tile = (t0 + tc) >> 5;
    int kin  = (t0 + tc) & 31;
    size_t dst = (size_t)tile*4096 + n*32 + kin;
    *(us8*)(vth + dst) = *(const us8*)&Th[n*72 + tc];
    *(us8*)(vtl + dst) = *(const us8*)&Tl[n*72 + tc];
  }
}

// ---- stats-only QK^T (swapped: S^T = K @ Q^T), per-(col-block,row) max/sumexp ----
__global__ __launch_bounds__(256) void k_stats(
    const u16* __restrict__ qh, const u16* __restrict__ ql,
    const u16* __restrict__ kh, const u16* __restrict__ kl,
    float* __restrict__ pmax, float* __restrict__ psum){
  __shared__ __align__(16) u16 Ah[128*40], Al[128*40], Bh[128*40], Bl[128*40];
  __shared__ float wst[2][128][2];
  int bm = blockIdx.y, bn = blockIdx.x;
  int tid = threadIdx.x;
  int lane = tid & 63, w = tid >> 6;
  int l15 = lane & 15, l4 = lane >> 4;
  int wr = w >> 1, wc = w & 1;          // wr: seq-half, wc: q-half
  int kg = l4 << 3;
  f32x4 accs[4][4] = {};                // [si(seq)][qi(q)]
  for (int kt = 0; kt < N; kt += 32){
    for (int c = tid; c < 512; c += 256){
      int r = c >> 2, k8 = (c & 3) << 3;
      size_t ga = (size_t)(bm*128 + r)*N + kt + k8;   // q rows
      size_t gb = (size_t)(bn*128 + r)*N + kt + k8;   // k rows (seq)
      int lo = r*40 + k8;
      *(us8*)&Ah[lo] = *(const us8*)(qh + ga);
      *(us8*)&Al[lo] = *(const us8*)(ql + ga);
      *(us8*)&Bh[lo] = *(const us8*)(kh + gb);
      *(us8*)&Bl[lo] = *(const us8*)(kl + gb);
    }
    __syncthreads();
    bf16x8 kfh[4], kfl[4], qfh[4], qfl[4];
#pragma unroll
    for (int si = 0; si < 4; ++si){
      kfh[si] = *(const bf16x8*)&Bh[(wr*64 + si*16 + l15)*40 + kg];
      kfl[si] = *(const bf16x8*)&Bl[(wr*64 + si*16 + l15)*40 + kg];
    }
#pragma unroll
    for (int qi = 0; qi < 4; ++qi){
      qfh[qi] = *(const bf16x8*)&Ah[(wc*64 + qi*16 + l15)*40 + kg];
      qfl[qi] = *(const bf16x8*)&Al[(wc*64 + qi*16 + l15)*40 + kg];
    }
#pragma unroll
    for (int si = 0; si < 4; ++si)
#pragma unroll
      for (int qi = 0; qi < 4; ++qi){
        accs[si][qi] = __builtin_amdgcn_mfma_f32_16x16x32_bf16(kfh[si], qfh[qi], accs[si][qi], 0,0,0);
        accs[si][qi] = __builtin_amdgcn_mfma_f32_16x16x32_bf16(kfh[si], qfl[qi], accs[si][qi], 0,0,0);
        accs[si][qi] = __builtin_amdgcn_mfma_f32_16x16x32_bf16(kfl[si], qfh[qi], accs[si][qi], 0,0,0);
      }
    __syncthreads();
  }
  float mq[4], sq[4];
#pragma unroll
  for (int qi = 0; qi < 4; ++qi){
    float m = -3.0e38f;
#pragma unroll
    for (int si = 0; si < 4; ++si)
#pragma unroll
      for (int r = 0; r < 4; ++r) m = fmaxf(m, accs[si][qi][r]);
    mq[qi] = m * SCL;
  }
#pragma unroll
  for (int qi = 0; qi < 4; ++qi){
    mq[qi] = fmaxf(mq[qi], __shfl_xor(mq[qi], 16, 64));
    mq[qi] = fmaxf(mq[qi], __shfl_xor(mq[qi], 32, 64));
  }
#pragma unroll
  for (int qi = 0; qi < 4; ++qi){
    float s = 0.0f;
#pragma unroll
    for (int si = 0; si < 4; ++si)
#pragma unroll
      for (int r = 0; r < 4; ++r) s += __expf(accs[si][qi][r]*SCL - mq[qi]);
    sq[qi] = s;
  }
#pragma unroll
  for (int qi = 0; qi < 4; ++qi){
    sq[qi] += __shfl_xor(sq[qi], 16, 64);
    sq[qi] += __shfl_xor(sq[qi], 32, 64);
  }
  if (l4 == 0){
#pragma unroll
    for (int qi = 0; qi < 4; ++qi){
      int ql_ = wc*64 + qi*16 + l15;
      wst[wr][ql_][0] = mq[qi];
      wst[wr][ql_][1] = sq[qi];
    }
  }
  __syncthreads();
  if (tid < 128){
    float m0 = wst[0][tid][0], m1 = wst[1][tid][0];
    float m = fmaxf(m0, m1);
    float Z = wst[0][tid][1]*__expf(m0 - m) + wst[1][tid][1]*__expf(m1 - m);
    pmax[(size_t)bn*S + bm*128 + tid] = m;
    psum[(size_t)bn*S + bm*128 + tid] = Z;
  }
}

// ---- merge per-col-block partials -> per-row (max, 1/Z) ----
__global__ void k_rowstat(const float* __restrict__ pmax, const float* __restrict__ psum,
                          float* __restrict__ rowm, float* __restrict__ rowinv){
  int t = blockIdx.x*256 + threadIdx.x;
  float m = -3.0e38f;
  for (int b = 0; b < 64; ++b) m = fmaxf(m, pmax[(size_t)b*S + t]);
  float Z = 0.0f;
  for (int b = 0; b < 64; ++b) Z += psum[(size_t)b*S + t]*__expf(pmax[(size_t)b*S + t] - m);
  rowm[t] = m;
  rowinv[t] = 1.0f/Z;
}

// ---- fused: recompute S^T, normalize, write attn, full-rate PV ----
// SLIM: 16 q-rows per wave; LDS = K (XOR-swz, 2x8KB) + V (stride-36, 2x9KB)
// = 34.8KB; acc = 32 regs. Goal: ~4 blocks/CU resident (vs 1 at r5).
__global__ __launch_bounds__(256) void k_ctx(
    float* __restrict__ attn,
    const float* __restrict__ rowm, const float* __restrict__ rowinv,
    const u16* __restrict__ qh, const u16* __restrict__ ql,
    const u16* __restrict__ kh, const u16* __restrict__ kl,
    const u16* __restrict__ vth, const u16* __restrict__ vtl,  // [S/32][128][32]
    float* __restrict__ dst, int mode){
  __shared__ __align__(16) u16 Ksh[32*128], Ksl[32*128];   // XOR-swizzled, 8KB each
  __shared__ __align__(16) u16 Vsh[128*36], Vsl[128*36];   // stride-36, 9KB each
  int bm = blockIdx.x, kz = blockIdx.y;
  int tid = threadIdx.x, lane = tid & 63, w = tid >> 6;
  int l15 = lane & 15, l4 = lane >> 4;
  int kg = l4 << 3;
  const int KC = S / KSPLIT;   // 512
  int k0 = kz*KC;
  int qbase = bm*64 + w*16;    // 16 q-rows per wave
  float rm = rowm[qbase + l15];
  float ri = rowinv[qbase + l15];
  // shfl source lanes for the exchange (g = j>>2)
  int src0 = l15 + 32*(l4 & 1);     // g = 0
  int src1 = src0 + 16;             // g = 1
  bool hi_si = (l4 >> 1);
  f32x4 acco[8] = {};   // [ni]
  for (int ko = 0; ko < KC; ko += 32){
    int cb = k0 + ko;
    // ---- stage K (XOR-swizzled) ----
    for (int c = tid; c < 512; c += 256){
      int rr = c >> 4, c8 = (c & 15) << 3;
      int lo = (rr*128 + c8) ^ ((rr & 7) << 3);
      size_t gk = (size_t)(cb + rr)*N + c8;
      *(us8*)&Ksh[lo] = *(const us8*)(kh + gk);
      *(us8*)&Ksl[lo] = *(const us8*)(kl + gk);
    }
    // ---- stage V (stride 36: conflict-free reads) ----
    {
      const u16* sh = vth + (size_t)(cb >> 5)*4096;
      const u16* sl = vtl + (size_t)(cb >> 5)*4096;
      for (int c = tid; c < 512; c += 256){
        int lo = (c >> 2)*36 + ((c & 3) << 3);
        *(us8*)&Vsh[lo] = *(const us8*)(sh + (size_t)c*8);
        *(us8*)&Vsl[lo] = *(const us8*)(sl + (size_t)c*8);
      }
    }
    __syncthreads();
    // ---- S^T: accs[si], K from LDS, Q from global (L1/L2-hot) ----
    f32x4 accs[2] = {};
#pragma unroll
    for (int kt = 0; kt < 4; ++kt){
      size_t gq = (size_t)(qbase + l15)*N + kt*32 + kg;
      bf16x8 qfh = *(const bf16x8*)(qh + gq);
      bf16x8 qfl = *(const bf16x8*)(ql + gq);
#pragma unroll
      for (int si = 0; si < 2; ++si){
        int lo = (((si*16 + l15)*128 + kt*32 + kg) ^ (((si*16 + l15) & 7) << 3));
        bf16x8 kfh = *(const bf16x8*)&Ksh[lo];
        bf16x8 kfl = *(const bf16x8*)&Ksl[lo];
        accs[si] = __builtin_amdgcn_mfma_f32_16x16x32_bf16(kfh, qfh, accs[si], 0,0,0);
        accs[si] = __builtin_amdgcn_mfma_f32_16x16x32_bf16(kfh, qfl, accs[si], 0,0,0);
        accs[si] = __builtin_amdgcn_mfma_f32_16x16x32_bf16(kfl, qfh, accs[si], 0,0,0);
      }
    }
    // ---- exchange -> y[j] = raw S at (q=qbase+l15, seq=cb+8*l4+j) ----
    float y[8];
#pragma unroll
    for (int r = 0; r < 4; ++r){
      float t0 = __shfl(accs[0][r], src0, 64);
      float t1 = __shfl(accs[1][r], src0, 64);
      y[r] = hi_si ? t1 : t0;
      float u0 = __shfl(accs[0][r], src1, 64);
      float u1 = __shfl(accs[1][r], src1, 64);
      y[4+r] = hi_si ? u1 : u0;
    }
    float p[8];
#pragma unroll
    for (int j = 0; j < 8; ++j) p[j] = __expf(y[j]*SCL - rm) * ri;
    {
      int q = qbase + l15;
      *(float4*)(attn + (size_t)q*S + cb + kg)     = make_float4(p[0],p[1],p[2],p[3]);
      *(float4*)(attn + (size_t)q*S + cb + kg + 4) = make_float4(p[4],p[5],p[6],p[7]);
    }
    bf16x8 pah, pal;
#pragma unroll
    for (int j = 0; j < 8; ++j){
      u16 h = f2bf(p[j]);
      pah[j] = (short)h;
      pal[j] = (short)f2bf(p[j] - bf2f(h));
    }
    // ---- PV full-rate: acco[ni] += P(32seq) x V ----
#pragma unroll
    for (int ni = 0; ni < 8; ++ni){
      int lo = (ni*16 + l15)*36 + kg;
      bf16x8 vbh = *(const bf16x8*)&Vsh[lo];
      bf16x8 vbl = *(const bf16x8*)&Vsl[lo];
      acco[ni] = __builtin_amdgcn_mfma_f32_16x16x32_bf16(pah, vbh, acco[ni], 0,0,0);
      acco[ni] = __builtin_amdgcn_mfma_f32_16x16x32_bf16(pah, vbl, acco[ni], 0,0,0);
      acco[ni] = __builtin_amdgcn_mfma_f32_16x16x32_bf16(pal, vbh, acco[ni], 0,0,0);
    }
    __syncthreads();   // before next iter's staging overwrites K/V
  }
  // epilogue: row q = qbase + 4*l4 + r, col n = ni*16 + l15
  if (mode == 0){
    float* P = dst + (size_t)kz*S*N;
#pragma unroll
    for (int ni = 0; ni < 8; ++ni)
#pragma unroll
      for (int r = 0; r < 4; ++r){
        int q = qbase + (l4<<2) + r;
        P[(size_t)q*N + ni*16 + l15] = acco[ni][r];
      }
  } else {
#pragma unroll
    for (int ni = 0; ni < 8; ++ni)
#pragma unroll
      for (int r = 0; r < 4; ++r){
        int q = qbase + (l4<<2) + r;
        atomicAdd(&dst[(size_t)q*N + ni*16 + l15], acco[ni][r]);
      }
  }
}

// ---- reduce partials -> ctx ----
__global__ __launch_bounds__(256) void k_reduce(const float* __restrict__ part,
                                                float* __restrict__ ctx){
  size_t idx = (size_t)blockIdx.x*256 + threadIdx.x;
  const float4* p4 = (const float4*)part;
  float4 acc = p4[idx];
  const size_t stride = (size_t)S*N/4;
#pragma unroll
  for (int kz = 1; kz < KSPLIT; ++kz){
    float4 v = p4[(size_t)kz*stride + idx];
    acc.x += v.x; acc.y += v.y; acc.z += v.z; acc.w += v.w;
  }
  ((float4*)ctx)[idx] = acc;
}

// ---- out = ctx @ Wp + bp ----
__global__ __launch_bounds__(256) void k_out(const float* __restrict__ ctx,
                   const float* __restrict__ Wp, const float* __restrict__ bp,
                   float* __restrict__ out){
  __shared__ __align__(16) float As[16][68];
  __shared__ __align__(16) float Bs[16][68];
  int bn = blockIdx.x;
  int bm = blockIdx.y;
  int tx = threadIdx.x, ty = threadIdx.y;
  int tid = ty*16 + tx;
  float acc[4][4] = {};
  for (int kt = 0; kt < N; kt += 16){
    int row = tid >> 2, kc = (tid & 3) << 2;
    float4 av = *(const float4*)(ctx + (size_t)(bm*64+row)*N + kt + kc);
    As[kc+0][row]=av.x; As[kc+1][row]=av.y; As[kc+2][row]=av.z; As[kc+3][row]=av.w;
    int bk = tid >> 4, c0 = (tid & 15) << 2;
#pragma unroll
    for (int jj = 0; jj < 4; ++jj){
      int c = bn*64 + c0 + jj;
      Bs[bk][c0+jj] = (c < OD) ? Wp[(size_t)(kt+bk)*OD + c] : 0.0f;
    }
    __syncthreads();
#pragma unroll
    for (int kk = 0; kk < 16; ++kk){
      float4 a = *(const float4*)&As[kk][ty*4];
      float4 b = *(const float4*)&Bs[kk][tx*4];
      float aa[4]={a.x,a.y,a.z,a.w}, bb[4]={b.x,b.y,b.z,b.w};
#pragma unroll
      for (int ii=0; ii<4; ++ii)
#pragma unroll
        for (int jj=0; jj<4; ++jj) acc[ii][jj] += aa[ii]*bb[jj];
    }
    __syncthreads();
  }
#pragma unroll
  for (int ii=0; ii<4; ++ii){
    int r = bm*64 + ty*4 + ii;
#pragma unroll
    for (int jj=0; jj<4; ++jj){
      int c = bn*64 + tx*4 + jj;
      if (c < OD) out[(size_t)r*OD + c] = acc[ii][jj] + bp[c];
    }
  }
}

extern "C" void kernel_launch(void* const* d_in, const int* in_sizes, int n_in,
                              void* d_out, int out_size, void* d_ws, size_t ws_size,
                              hipStream_t stream){
  const float* fq = (const float*)d_in[0];
  const float* fk = (const float*)d_in[1];
  const float* fv = (const float*)d_in[2];
  const float* GA = (const float*)d_in[3];
  const float* GB = (const float*)d_in[4];
  const float* Wp = (const float*)d_in[5];
  const float* bp = (const float*)d_in[6];
  float* out  = (float*)d_out;
  float* attn = out + (size_t)S*OD;

  float* ws     = (float*)d_ws;
  float* QT     = ws;                                // 129*16384
  float* g      = QT + (size_t)129*N*N;              // 128*128
  float* bounds = g + (size_t)L*N;                   // 65*3*128
  float* cs     = bounds + (size_t)(NC+1)*3*N;       // 3*8192*128
  float* ctx    = cs + (size_t)3*S*N;                // 8192*128
  u16*   qkh    = (u16*)(ctx + (size_t)S*N);         // 2*S*N u16
  u16*   qkl    = qkh + (size_t)2*S*N;               // 2*S*N u16
  u16*   vth    = qkl + (size_t)2*S*N;               // S*N u16 tiled [S/32][128][32]
  u16*   vtl    = vth + (size_t)S*N;                 // S*N u16
  float* pmax   = (float*)(vtl + (size_t)S*N);       // 64*8192
  float* psum   = pmax + (size_t)(S/128)*S;          // 64*8192
  float* rowm   = psum + (size_t)(S/128)*S;          // 8192
  float* rowinv = rowm + S;                          // 8192
  float* part   = rowinv + S;                        // KSPLIT*8192*128 (optional)
  size_t need_part = ((size_t)(part - ws) + (size_t)KSPLIT*S*N) * sizeof(float);
  bool use_part = (ws_size >= need_part);

  k_copyT<<<64, 256, 0, stream>>>(GA, QT + (size_t)N*N);
  for (int m = 1; m < L; m <<= 1)
    k_powmm<<<dim3(2,2,m), dim3(16,16), 0, stream>>>(QT, m);
  k_g<<<128, 128, 0, stream>>>(QT, GB, g);
  k_fill_local<<<dim3(4,3,NC), dim3(16,16), 0, stream>>>(fq, fk, fv, g, cs);
  k_bscan<<<1, 384, 0, stream>>>(QT, cs, bounds);
  k_fill_bound<<<dim3(L,4), 256, 0, stream>>>(QT, bounds, cs);

  k_split_qk<<<(2*S*N)/1024, 256, 0, stream>>>(cs, qkh, qkl);
  k_split_vT<<<S/64, 256, 0, stream>>>(cs + (size_t)2*S*N, vth, vtl);

  k_stats<<<dim3(S/128, S/128), 256, 0, stream>>>(
      qkh, qkl, qkh + (size_t)S*N, qkl + (size_t)S*N, pmax, psum);
  k_rowstat<<<S/256, 256, 0, stream>>>(pmax, psum, rowm, rowinv);
  if (use_part){
    k_ctx<<<dim3(S/64, KSPLIT), 256, 0, stream>>>(attn, rowm, rowinv,
        qkh, qkl, qkh + (size_t)S*N, qkl + (size_t)S*N, vth, vtl, part, 0);
    k_reduce<<<(S*N/4)/256, 256, 0, stream>>>(part, ctx);
  } else {
    hipMemsetAsync(ctx, 0, (size_t)S*N*sizeof(float), stream);
    k_ctx<<<dim3(S/64, KSPLIT), 256, 0, stream>>>(attn, rowm, rowinv,
        qkh, qkl, qkh + (size_t)S*N, qkl + (size_t)S*N, vth, vtl, ctx, 1);
  }
  k_out<<<dim3(16, S/64), dim3(16,16), 0, stream>>>(ctx, Wp, bp, out);
}